// Round 1
// baseline (5269.030 us; speedup 1.0000x reference)
//
#include <hip/hip_runtime.h>

// RGCN_9929964388947: hetero 2-layer GraphConv (mean aggr) on MI355X.
// Structure per conv: msg = segment_sum(x_src[ei0], ei1); mean = msg/deg;
//                     y = relu(mean @ wrel.T + brel + x_dst @ wroot.T + x_dst)
// fp32 end-to-end.

#define FDIM 64

// ---- degree count: one thread per edge, atomic +1 at dst ----
__global__ __launch_bounds__(256) void k_count_deg(const int* __restrict__ dst, int E,
                                                   float* __restrict__ deg) {
  int i = blockIdx.x * 256 + threadIdx.x;
  if (i < E) atomicAdd(&deg[dst[i]], 1.0f);
}

// ---- y[N,64] = x[N,64] @ W[64,64].T + b ; one wave per row, lane = out chan ----
__global__ __launch_bounds__(256) void k_linear64(const float* __restrict__ x,
                                                  const float* __restrict__ W,
                                                  const float* __restrict__ b,
                                                  float* __restrict__ y, int N) {
  __shared__ float Wt[64 * 64];  // Wt[k*64+o] = W[o*64+k]  (transposed: lane-consecutive)
  __shared__ float bs[64];
  int t = threadIdx.x;
  for (int idx = t; idx < 64 * 64; idx += 256) {
    int o = idx >> 6, k = idx & 63;
    Wt[(k << 6) | o] = W[idx];
  }
  if (t < 64) bs[t] = b[t];
  __syncthreads();
  int wave = t >> 6, lane = t & 63;
  for (int r = blockIdx.x * 4 + wave; r < N; r += gridDim.x * 4) {
    float xv = x[r * 64 + lane];   // row is wave-uniform; lane k holds x[r][k]
    float acc = bs[lane];
#pragma unroll
    for (int k = 0; k < 64; ++k) {
      acc = fmaf(__shfl(xv, k, 64), Wt[(k << 6) | lane], acc);
    }
    y[r * 64 + lane] = acc;
  }
}

// ---- scatter: one wave per edge; lane f does msg[d][f] += x_src[s][f] ----
__global__ __launch_bounds__(256) void k_scatter(const float* __restrict__ xsrc,
                                                 const int* __restrict__ src,
                                                 const int* __restrict__ dst, int E,
                                                 float* __restrict__ msg) {
  int wave = threadIdx.x >> 6, lane = threadIdx.x & 63;
  int e = blockIdx.x * 4 + wave;
  if (e < E) {
    int s = src[e];  // same address all lanes -> single broadcast request
    int d = dst[e];
    float v = xsrc[(size_t)s * 64 + lane];
    atomicAdd(&msg[(size_t)d * 64 + lane], v);
  }
}

// ---- conv combine: y = relu(msg/deg @ wrel.T + brel + xdst @ wroot.T + xdst) ----
__global__ __launch_bounds__(256) void k_conv_post(const float* __restrict__ msg,
                                                   const float* __restrict__ deg,
                                                   const float* __restrict__ xdst,
                                                   const float* __restrict__ wrel,
                                                   const float* __restrict__ brel,
                                                   const float* __restrict__ wroot,
                                                   float* __restrict__ y, int N) {
  __shared__ float WrT[64 * 64];
  __shared__ float WoT[64 * 64];
  __shared__ float bs[64];
  int t = threadIdx.x;
  for (int idx = t; idx < 64 * 64; idx += 256) {
    int o = idx >> 6, k = idx & 63;
    WrT[(k << 6) | o] = wrel[idx];
    WoT[(k << 6) | o] = wroot[idx];
  }
  if (t < 64) bs[t] = brel[t];
  __syncthreads();
  int wave = t >> 6, lane = t & 63;
  for (int r = blockIdx.x * 4 + wave; r < N; r += gridDim.x * 4) {
    float scale = 1.0f / fmaxf(deg[r], 1.0f);
    float mv = msg[r * 64 + lane] * scale;
    float xv = xdst[r * 64 + lane];
    float acc = bs[lane];
#pragma unroll
    for (int k = 0; k < 64; ++k) {
      acc = fmaf(__shfl(mv, k, 64), WrT[(k << 6) | lane], acc);
      acc = fmaf(__shfl(xv, k, 64), WoT[(k << 6) | lane], acc);
    }
    y[r * 64 + lane] = fmaxf(acc + xv, 0.0f);
  }
}

// ---- post linear: y[N,32] = x[N,64] @ W[32,64].T + b ; 32-lane group per row ----
__global__ __launch_bounds__(256) void k_postlin(const float* __restrict__ x,
                                                 const float* __restrict__ W,
                                                 const float* __restrict__ b,
                                                 float* __restrict__ y, int N) {
  __shared__ float Wt[64 * 32];  // Wt[k*32+o] = W[o*64+k]
  __shared__ float bs[32];
  int t = threadIdx.x;
  for (int idx = t; idx < 32 * 64; idx += 256) {
    int o = idx >> 6, k = idx & 63;
    Wt[(k << 5) | o] = W[idx];
  }
  if (t < 32) bs[t] = b[t];
  __syncthreads();
  int grp = t >> 5, o = t & 31;  // 8 rows per block
  for (int r = blockIdx.x * 8 + grp; r < N; r += gridDim.x * 8) {
    float xv0 = x[r * 64 + o];
    float xv1 = x[r * 64 + 32 + o];
    float acc = bs[o];
#pragma unroll
    for (int k = 0; k < 32; ++k) {
      acc = fmaf(__shfl(xv0, k, 32), Wt[(k << 5) | o], acc);
      acc = fmaf(__shfl(xv1, k, 32), Wt[((k + 32) << 5) | o], acc);
    }
    y[(size_t)r * 32 + o] = acc;
  }
}

extern "C" void kernel_launch(void* const* d_in, const int* in_sizes, int n_in,
                              void* d_out, int out_size, void* d_ws, size_t ws_size,
                              hipStream_t stream) {
  const float* x_user = (const float*)d_in[0];
  const float* x_item = (const float*)d_in[1];
  const int* ei_u2i = (const int*)d_in[2];
  const int* ei_i2u = (const int*)d_in[3];
  const float* pre_w_user = (const float*)d_in[4];
  const float* pre_b_user = (const float*)d_in[5];
  const float* pre_w_item = (const float*)d_in[6];
  const float* pre_b_item = (const float*)d_in[7];
  // c1_u2i: wrel=8 brel=9 wroot=10 ; c1_i2u: 11,12,13 ; c2_u2i: 14,15,16 ; c2_i2u: 17,18,19
  const float* post_w_user = (const float*)d_in[20];
  const float* post_b_user = (const float*)d_in[21];
  const float* post_w_item = (const float*)d_in[22];
  const float* post_b_item = (const float*)d_in[23];

  const int NU = in_sizes[0] / FDIM;
  const int NI = in_sizes[1] / FDIM;
  const int E = in_sizes[2] / 2;

  // workspace layout (fp32): h_u | h_i | x1_u | x1_i | msg(max NU rows) | deg_u | deg_i
  float* ws = (float*)d_ws;
  float* h_u = ws;  ws += (size_t)NU * FDIM;
  float* h_i = ws;  ws += (size_t)NI * FDIM;
  float* x1_u = ws; ws += (size_t)NU * FDIM;
  float* x1_i = ws; ws += (size_t)NI * FDIM;
  float* msg = ws;  ws += (size_t)NU * FDIM;
  float* deg_u = ws; ws += NU;
  float* deg_i = ws; ws += NI;

  const int* u2i_src = ei_u2i;
  const int* u2i_dst = ei_u2i + E;
  const int* i2u_src = ei_i2u;
  const int* i2u_dst = ei_i2u + E;

  const int gE1 = (E + 255) / 256;   // 1 thread/edge
  const int gE4 = (E + 3) / 4;       // 1 wave/edge, 4 waves/block
  const int gU = (NU + 3) / 4;
  const int gI = (NI + 3) / 4;

  // degrees (same edge lists reused by both layers)
  hipMemsetAsync(deg_u, 0, (size_t)NU * sizeof(float), stream);
  hipMemsetAsync(deg_i, 0, (size_t)NI * sizeof(float), stream);
  k_count_deg<<<gE1, 256, 0, stream>>>(u2i_dst, E, deg_i);
  k_count_deg<<<gE1, 256, 0, stream>>>(i2u_dst, E, deg_u);

  // pre linears
  k_linear64<<<gU, 256, 0, stream>>>(x_user, pre_w_user, pre_b_user, h_u, NU);
  k_linear64<<<gI, 256, 0, stream>>>(x_item, pre_w_item, pre_b_item, h_i, NI);

  // ---- layer 1, item dst (u2i) ----
  hipMemsetAsync(msg, 0, (size_t)NI * FDIM * sizeof(float), stream);
  k_scatter<<<gE4, 256, 0, stream>>>(h_u, u2i_src, u2i_dst, E, msg);
  k_conv_post<<<gI, 256, 0, stream>>>(msg, deg_i, h_i, (const float*)d_in[8],
                                      (const float*)d_in[9], (const float*)d_in[10], x1_i, NI);
  // ---- layer 1, user dst (i2u) ----
  hipMemsetAsync(msg, 0, (size_t)NU * FDIM * sizeof(float), stream);
  k_scatter<<<gE4, 256, 0, stream>>>(h_i, i2u_src, i2u_dst, E, msg);
  k_conv_post<<<gU, 256, 0, stream>>>(msg, deg_u, h_u, (const float*)d_in[11],
                                      (const float*)d_in[12], (const float*)d_in[13], x1_u, NU);

  // ---- layer 2, item dst -> x2_i overwrites h_i ----
  hipMemsetAsync(msg, 0, (size_t)NI * FDIM * sizeof(float), stream);
  k_scatter<<<gE4, 256, 0, stream>>>(x1_u, u2i_src, u2i_dst, E, msg);
  k_conv_post<<<gI, 256, 0, stream>>>(msg, deg_i, x1_i, (const float*)d_in[14],
                                      (const float*)d_in[15], (const float*)d_in[16], h_i, NI);
  // ---- layer 2, user dst -> x2_u overwrites h_u ----
  hipMemsetAsync(msg, 0, (size_t)NU * FDIM * sizeof(float), stream);
  k_scatter<<<gE4, 256, 0, stream>>>(x1_i, i2u_src, i2u_dst, E, msg);
  k_conv_post<<<gU, 256, 0, stream>>>(msg, deg_u, x1_u, (const float*)d_in[17],
                                      (const float*)d_in[18], (const float*)d_in[19], h_u, NU);

  // post linears -> d_out = [out_u (NU*32) | out_i (NI*32)]
  float* out = (float*)d_out;
  k_postlin<<<(NU + 7) / 8, 256, 0, stream>>>(h_u, post_w_user, post_b_user, out, NU);
  k_postlin<<<(NI + 7) / 8, 256, 0, stream>>>(h_i, post_w_item, post_b_item,
                                              out + (size_t)NU * 32, NI);
}

// Round 2
// 1495.475 us; speedup vs baseline: 3.5233x; 3.5233x over previous
//
#include <hip/hip_runtime.h>

// RGCN: hetero 2-layer GraphConv (mean aggr), fp32, MI355X.
// R2: replace shuffle-GEMV conv (64-way LDS staging conflicts, 4x1050us) with
// register-tiled fp32 GEMM: 128x64 tile, 8x4 acc/thread, b128 LDS reads,
// XOR-swizzled granules (conflict-free verified by hand per m136 bank rules).

#define FDIM 64

// ---- degree count ----
__global__ __launch_bounds__(256) void k_count_deg(const int* __restrict__ dst, int E,
                                                   float* __restrict__ deg) {
  int i = blockIdx.x * 256 + threadIdx.x;
  if (i < E) atomicAdd(&deg[dst[i]], 1.0f);
}

// ---- scatter: one wave per edge; lane f does msg[d][f] += x_src[s][f] ----
__global__ __launch_bounds__(256) void k_scatter(const float* __restrict__ xsrc,
                                                 const int* __restrict__ src,
                                                 const int* __restrict__ dst, int E,
                                                 float* __restrict__ msg) {
  int wave = threadIdx.x >> 6, lane = threadIdx.x & 63;
  int e = blockIdx.x * 4 + wave;
  if (e < E) {
    int s = src[e];  // wave-uniform -> scalar broadcast
    int d = dst[e];
    float v = xsrc[(size_t)s * 64 + lane];
    atomicAdd(&msg[(size_t)d * 64 + lane], v);
  }
}

// ---- fused GEMM: Y[N,64] = act( A1*(1/deg?) @ W1^T + A2 @ (W2 + skip*I)^T + b )
// Tile: 128 rows x 64 cols, 256 threads, thread = 8 rows (ty=t>>4) x 4 cols (tx=t&15).
// LDS layout: As[r][68 floats], granule (4-float) q stored at q ^ (r>>3).
//             Bs[c][68 floats], granule q stored at q ^ (c>>3).
// Verified banks: A-reads 4 distinct quads/instr (16-lane bcast), B-reads 2-way,
// staging writes perfectly even over 8 quads (b128 floor).
__global__ __launch_bounds__(256) void k_gemm64(
    const float* __restrict__ A1, const float* __restrict__ deg,
    const float* __restrict__ A2,
    const float* __restrict__ W1, const float* __restrict__ W2,
    const float* __restrict__ bias, int addskip, int dorelu,
    float* __restrict__ Y, int N) {
  __shared__ float As[128 * 68];
  __shared__ float Bs[64 * 68];
  const int t = threadIdx.x;
  const int tx = t & 15, ty = t >> 4;
  const int row0 = blockIdx.x * 128;

  float acc[8][4];
#pragma unroll
  for (int i = 0; i < 8; ++i)
#pragma unroll
    for (int j = 0; j < 4; ++j) acc[i][j] = 0.0f;

  const int nh = (A2 != nullptr) ? 2 : 1;
  for (int h = 0; h < nh; ++h) {
    const float* A = (h == 0) ? A1 : A2;
    const float* W = (h == 0) ? W1 : W2;
    const float* dg = (h == 0) ? deg : nullptr;
    __syncthreads();  // protect previous half's reads before restaging
    // stage B: 64 rows x 16 float4, coalesced global read, swizzled LDS write
    {
      const float4* Wv = (const float4*)W;
#pragma unroll
      for (int it = 0; it < 4; ++it) {
        int idx = t + it * 256;  // 0..1023
        int c = idx >> 4, q = idx & 15;
        float4 v = Wv[idx];  // W[c][4q..4q+3]
        if (addskip && h == 1 && (c >> 2) == q) (&v.x)[c & 3] += 1.0f;  // W2 + I
        *(float4*)&Bs[c * 68 + ((q ^ (c >> 3)) << 2)] = v;
      }
    }
    // stage A: 128 rows x 16 float4 (zero-padded past N, deg-scaled if dg)
    {
      const float4* Av = (const float4*)A;
#pragma unroll
      for (int it = 0; it < 8; ++it) {
        int idx = t + it * 256;  // 0..2047
        int r = idx >> 4, q = idx & 15;
        int gr = row0 + r;
        float4 v = make_float4(0.f, 0.f, 0.f, 0.f);
        if (gr < N) {
          v = Av[(size_t)gr * 16 + q];
          if (dg) {
            float s = 1.0f / fmaxf(dg[gr], 1.0f);
            v.x *= s; v.y *= s; v.z *= s; v.w *= s;
          }
        }
        *(float4*)&As[r * 68 + ((q ^ (r >> 3)) << 2)] = v;
      }
    }
    __syncthreads();
    // inner loop: 16 k-quads; 12 b128 + 128 FMA per thread per kq
    const int bsw = tx >> 1;  // (4tx+j)>>3, uniform over j
#pragma unroll 4
    for (int kq = 0; kq < 16; ++kq) {
      float4 b[4];
      const int bq = (kq ^ bsw) << 2;
#pragma unroll
      for (int j = 0; j < 4; ++j)
        b[j] = *(const float4*)&Bs[(tx * 4 + j) * 68 + bq];
      const int aq = (kq ^ ty) << 2;  // (8ty+i)>>3 == ty, uniform over i
#pragma unroll
      for (int i = 0; i < 8; ++i) {
        float4 a = *(const float4*)&As[(ty * 8 + i) * 68 + aq];
#pragma unroll
        for (int j = 0; j < 4; ++j) {
          acc[i][j] = fmaf(a.x, b[j].x, acc[i][j]);
          acc[i][j] = fmaf(a.y, b[j].y, acc[i][j]);
          acc[i][j] = fmaf(a.z, b[j].z, acc[i][j]);
          acc[i][j] = fmaf(a.w, b[j].w, acc[i][j]);
        }
      }
    }
  }
  // epilogue: + bias, optional relu, coalesced float4 store
  float4 bv = ((const float4*)bias)[tx];
#pragma unroll
  for (int i = 0; i < 8; ++i) {
    int gr = row0 + ty * 8 + i;
    if (gr < N) {
      float4 o;
      o.x = acc[i][0] + bv.x; o.y = acc[i][1] + bv.y;
      o.z = acc[i][2] + bv.z; o.w = acc[i][3] + bv.w;
      if (dorelu) {
        o.x = fmaxf(o.x, 0.f); o.y = fmaxf(o.y, 0.f);
        o.z = fmaxf(o.z, 0.f); o.w = fmaxf(o.w, 0.f);
      }
      ((float4*)Y)[(size_t)gr * 16 + tx] = o;
    }
  }
}

// ---- post linear: Y[N,32] = A @ W^T + b ; tile 128 rows x 32 cols,
// thread = 4 rows (ty=t>>3) x 4 cols (tx=t&7), same swizzle scheme ----
__global__ __launch_bounds__(256) void k_postlin32(
    const float* __restrict__ A, const float* __restrict__ W,
    const float* __restrict__ bias, float* __restrict__ Y, int N) {
  __shared__ float As[128 * 68];
  __shared__ float Bs[32 * 68];
  const int t = threadIdx.x;
  const int tx = t & 7, ty = t >> 3;
  const int row0 = blockIdx.x * 128;

  float acc[4][4];
#pragma unroll
  for (int i = 0; i < 4; ++i)
#pragma unroll
    for (int j = 0; j < 4; ++j) acc[i][j] = 0.0f;

  // stage B: 32 rows x 16 float4
  {
    const float4* Wv = (const float4*)W;
#pragma unroll
    for (int it = 0; it < 2; ++it) {
      int idx = t + it * 256;  // 0..511
      int c = idx >> 4, q = idx & 15;
      float4 v = Wv[idx];
      *(float4*)&Bs[c * 68 + ((q ^ (c >> 3)) << 2)] = v;
    }
  }
  // stage A
  {
    const float4* Av = (const float4*)A;
#pragma unroll
    for (int it = 0; it < 8; ++it) {
      int idx = t + it * 256;
      int r = idx >> 4, q = idx & 15;
      int gr = row0 + r;
      float4 v = make_float4(0.f, 0.f, 0.f, 0.f);
      if (gr < N) v = Av[(size_t)gr * 16 + q];
      *(float4*)&As[r * 68 + ((q ^ (r >> 3)) << 2)] = v;
    }
  }
  __syncthreads();
  const int bsw = tx >> 1;
  const int asw = ty >> 1;  // (4ty+i)>>3, uniform over i
#pragma unroll 4
  for (int kq = 0; kq < 16; ++kq) {
    float4 b[4];
    const int bq = (kq ^ bsw) << 2;
#pragma unroll
    for (int j = 0; j < 4; ++j)
      b[j] = *(const float4*)&Bs[(tx * 4 + j) * 68 + bq];
    const int aq = (kq ^ asw) << 2;
#pragma unroll
    for (int i = 0; i < 4; ++i) {
      float4 a = *(const float4*)&As[(ty * 4 + i) * 68 + aq];
#pragma unroll
      for (int j = 0; j < 4; ++j) {
        acc[i][j] = fmaf(a.x, b[j].x, acc[i][j]);
        acc[i][j] = fmaf(a.y, b[j].y, acc[i][j]);
        acc[i][j] = fmaf(a.z, b[j].z, acc[i][j]);
        acc[i][j] = fmaf(a.w, b[j].w, acc[i][j]);
      }
    }
  }
  float4 bv = ((const float4*)bias)[tx];
#pragma unroll
  for (int i = 0; i < 4; ++i) {
    int gr = row0 + ty * 4 + i;
    if (gr < N) {
      float4 o;
      o.x = acc[i][0] + bv.x; o.y = acc[i][1] + bv.y;
      o.z = acc[i][2] + bv.z; o.w = acc[i][3] + bv.w;
      ((float4*)Y)[(size_t)gr * 8 + tx] = o;
    }
  }
}

extern "C" void kernel_launch(void* const* d_in, const int* in_sizes, int n_in,
                              void* d_out, int out_size, void* d_ws, size_t ws_size,
                              hipStream_t stream) {
  const float* x_user = (const float*)d_in[0];
  const float* x_item = (const float*)d_in[1];
  const int* ei_u2i = (const int*)d_in[2];
  const int* ei_i2u = (const int*)d_in[3];
  const float* pre_w_user = (const float*)d_in[4];
  const float* pre_b_user = (const float*)d_in[5];
  const float* pre_w_item = (const float*)d_in[6];
  const float* pre_b_item = (const float*)d_in[7];
  const float* post_w_user = (const float*)d_in[20];
  const float* post_b_user = (const float*)d_in[21];
  const float* post_w_item = (const float*)d_in[22];
  const float* post_b_item = (const float*)d_in[23];

  const int NU = in_sizes[0] / FDIM;
  const int NI = in_sizes[1] / FDIM;
  const int E = in_sizes[2] / 2;

  float* ws = (float*)d_ws;
  float* h_u = ws;  ws += (size_t)NU * FDIM;
  float* h_i = ws;  ws += (size_t)NI * FDIM;
  float* x1_u = ws; ws += (size_t)NU * FDIM;
  float* x1_i = ws; ws += (size_t)NI * FDIM;
  float* msg = ws;  ws += (size_t)NU * FDIM;
  float* deg_u = ws; ws += NU;
  float* deg_i = ws; ws += NI;

  const int* u2i_src = ei_u2i;
  const int* u2i_dst = ei_u2i + E;
  const int* i2u_src = ei_i2u;
  const int* i2u_dst = ei_i2u + E;

  const int gE1 = (E + 255) / 256;
  const int gE4 = (E + 3) / 4;
  const int tU = (NU + 127) / 128;  // gemm tiles
  const int tI = (NI + 127) / 128;

  hipMemsetAsync(deg_u, 0, (size_t)NU * sizeof(float), stream);
  hipMemsetAsync(deg_i, 0, (size_t)NI * sizeof(float), stream);
  k_count_deg<<<gE1, 256, 0, stream>>>(u2i_dst, E, deg_i);
  k_count_deg<<<gE1, 256, 0, stream>>>(i2u_dst, E, deg_u);

  // pre linears (no relu)
  k_gemm64<<<tU, 256, 0, stream>>>(x_user, nullptr, nullptr, pre_w_user, nullptr,
                                   pre_b_user, 0, 0, h_u, NU);
  k_gemm64<<<tI, 256, 0, stream>>>(x_item, nullptr, nullptr, pre_w_item, nullptr,
                                   pre_b_item, 0, 0, h_i, NI);

  // ---- layer 1, item dst (u2i) ----
  hipMemsetAsync(msg, 0, (size_t)NI * FDIM * sizeof(float), stream);
  k_scatter<<<gE4, 256, 0, stream>>>(h_u, u2i_src, u2i_dst, E, msg);
  k_gemm64<<<tI, 256, 0, stream>>>(msg, deg_i, h_i, (const float*)d_in[8],
                                   (const float*)d_in[10], (const float*)d_in[9],
                                   1, 1, x1_i, NI);
  // ---- layer 1, user dst (i2u) ----
  hipMemsetAsync(msg, 0, (size_t)NU * FDIM * sizeof(float), stream);
  k_scatter<<<gE4, 256, 0, stream>>>(h_i, i2u_src, i2u_dst, E, msg);
  k_gemm64<<<tU, 256, 0, stream>>>(msg, deg_u, h_u, (const float*)d_in[11],
                                   (const float*)d_in[13], (const float*)d_in[12],
                                   1, 1, x1_u, NU);

  // ---- layer 2, item dst -> overwrites h_i ----
  hipMemsetAsync(msg, 0, (size_t)NI * FDIM * sizeof(float), stream);
  k_scatter<<<gE4, 256, 0, stream>>>(x1_u, u2i_src, u2i_dst, E, msg);
  k_gemm64<<<tI, 256, 0, stream>>>(msg, deg_i, x1_i, (const float*)d_in[14],
                                   (const float*)d_in[16], (const float*)d_in[15],
                                   1, 1, h_i, NI);
  // ---- layer 2, user dst -> overwrites h_u ----
  hipMemsetAsync(msg, 0, (size_t)NU * FDIM * sizeof(float), stream);
  k_scatter<<<gE4, 256, 0, stream>>>(x1_i, i2u_src, i2u_dst, E, msg);
  k_gemm64<<<tU, 256, 0, stream>>>(msg, deg_u, x1_u, (const float*)d_in[17],
                                   (const float*)d_in[19], (const float*)d_in[18],
                                   1, 1, h_u, NU);

  // post linears -> d_out = [out_u | out_i]
  float* out = (float*)d_out;
  k_postlin32<<<tU, 256, 0, stream>>>(h_u, post_w_user, post_b_user, out, NU);
  k_postlin32<<<tI, 256, 0, stream>>>(h_i, post_w_item, post_b_item,
                                      out + (size_t)NU * 32, NI);
}

// Round 3
// 950.503 us; speedup vs baseline: 5.5434x; 1.5734x over previous
//
#include <hip/hip_runtime.h>

// RGCN: hetero 2-layer GraphConv (mean aggr), fp32, MI355X.
// R3: kill the atomic scatter (L2 atomic-slot bound at ~292G atomics/s).
// Build CSR-by-dst per edge type (count -> scan -> counting-sort fill),
// aggregate with a wave-per-dst gather-sum (256B coalesced row reads, no
// atomics), mean fused into the gather. Dense GEMMs unchanged from R2.

#define FDIM 64

// ---- degree count (int) ----
__global__ __launch_bounds__(256) void k_count_deg(const int* __restrict__ dst, int E,
                                                   int* __restrict__ cnt) {
  int i = blockIdx.x * 256 + threadIdx.x;
  if (i < E) atomicAdd(&cnt[dst[i]], 1);
}

// ---- scan stage 1: per-block (2048 elems) exclusive scan + block sums ----
__global__ __launch_bounds__(256) void k_scan1(const int* __restrict__ cnt, int n,
                                               int* __restrict__ excl,
                                               int* __restrict__ partials) {
  __shared__ int sd[256];
  int t = threadIdx.x;
  int base = blockIdx.x * 2048 + t * 8;
  int v[8]; int local = 0;
#pragma unroll
  for (int i = 0; i < 8; ++i) {
    int idx = base + i;
    int x = (idx < n) ? cnt[idx] : 0;
    v[i] = x; local += x;
  }
  sd[t] = local; __syncthreads();
  int sum = local;
  for (int off = 1; off < 256; off <<= 1) {
    int x = (t >= off) ? sd[t - off] : 0;
    __syncthreads();
    sum += x; sd[t] = sum;
    __syncthreads();
  }
  if (t == 255) partials[blockIdx.x] = sum;
  int run = sum - local;  // exclusive prefix of this thread's chunk
#pragma unroll
  for (int i = 0; i < 8; ++i) {
    int idx = base + i;
    if (idx < n) excl[idx] = run;
    run += v[i];
  }
}

// ---- scan stage 2: exclusive scan of block sums (nb <= 256), in place ----
__global__ __launch_bounds__(256) void k_scan2(int* __restrict__ partials, int nb) {
  __shared__ int sd[256];
  int t = threadIdx.x;
  int v = (t < nb) ? partials[t] : 0;
  sd[t] = v; __syncthreads();
  int sum = v;
  for (int off = 1; off < 256; off <<= 1) {
    int x = (t >= off) ? sd[t - off] : 0;
    __syncthreads();
    sum += x; sd[t] = sum;
    __syncthreads();
  }
  if (t < nb) partials[t] = sum - v;
}

// ---- scan stage 3: add block offset; write offsets + cursor copy ----
__global__ __launch_bounds__(256) void k_scan3(int* __restrict__ off,
                                               const int* __restrict__ partials, int n,
                                               int total, int* __restrict__ cursor) {
  int idx = blockIdx.x * 256 + threadIdx.x;
  if (idx < n) {
    int v = off[idx] + partials[idx >> 11];
    off[idx] = v;
    cursor[idx] = v;
  }
  if (idx == 0) off[n] = total;
}

// ---- counting-sort fill: csr[pos] = src edge endpoint ----
__global__ __launch_bounds__(256) void k_fill(const int* __restrict__ src,
                                              const int* __restrict__ dst, int E,
                                              int* __restrict__ cursor,
                                              int* __restrict__ csr) {
  int e = blockIdx.x * 256 + threadIdx.x;
  if (e < E) {
    int d = dst[e];
    int p = atomicAdd(&cursor[d], 1);
    csr[p] = src[e];
  }
}

// ---- gather-mean: one wave per dst row, lane = feature ----
__global__ __launch_bounds__(256) void k_gather_mean(const float* __restrict__ xsrc,
                                                     const int* __restrict__ off,
                                                     const int* __restrict__ csr,
                                                     float* __restrict__ msg, int N) {
  int wave = threadIdx.x >> 6, lane = threadIdx.x & 63;
  int d = blockIdx.x * 4 + wave;
  if (d >= N) return;
  int beg = off[d], end = off[d + 1];
  float a0 = 0.f, a1 = 0.f, a2 = 0.f, a3 = 0.f;
  int j = beg;
  for (; j + 4 <= end; j += 4) {
    int s0 = csr[j], s1 = csr[j + 1], s2 = csr[j + 2], s3 = csr[j + 3];
    a0 += xsrc[(size_t)s0 * 64 + lane];
    a1 += xsrc[(size_t)s1 * 64 + lane];
    a2 += xsrc[(size_t)s2 * 64 + lane];
    a3 += xsrc[(size_t)s3 * 64 + lane];
  }
  for (; j < end; ++j) a0 += xsrc[(size_t)csr[j] * 64 + lane];
  float acc = (a0 + a1) + (a2 + a3);
  float scale = 1.0f / fmaxf((float)(end - beg), 1.0f);
  msg[(size_t)d * 64 + lane] = acc * scale;
}

// ---- fused GEMM: Y[N,64] = act( A1 @ W1^T + A2 @ (W2 + skip*I)^T + b ) ----
// Tile 128x64, 256 threads, thread = 8 rows x 4 cols, XOR-swizzled b128 LDS.
__global__ __launch_bounds__(256) void k_gemm64(
    const float* __restrict__ A1, const float* __restrict__ A2,
    const float* __restrict__ W1, const float* __restrict__ W2,
    const float* __restrict__ bias, int addskip, int dorelu,
    float* __restrict__ Y, int N) {
  __shared__ float As[128 * 68];
  __shared__ float Bs[64 * 68];
  const int t = threadIdx.x;
  const int tx = t & 15, ty = t >> 4;
  const int row0 = blockIdx.x * 128;

  float acc[8][4];
#pragma unroll
  for (int i = 0; i < 8; ++i)
#pragma unroll
    for (int j = 0; j < 4; ++j) acc[i][j] = 0.0f;

  const int nh = (A2 != nullptr) ? 2 : 1;
  for (int h = 0; h < nh; ++h) {
    const float* A = (h == 0) ? A1 : A2;
    const float* W = (h == 0) ? W1 : W2;
    __syncthreads();
    {
      const float4* Wv = (const float4*)W;
#pragma unroll
      for (int it = 0; it < 4; ++it) {
        int idx = t + it * 256;
        int c = idx >> 4, q = idx & 15;
        float4 v = Wv[idx];
        if (addskip && h == 1 && (c >> 2) == q) (&v.x)[c & 3] += 1.0f;  // W2 + I
        *(float4*)&Bs[c * 68 + ((q ^ (c >> 3)) << 2)] = v;
      }
    }
    {
      const float4* Av = (const float4*)A;
#pragma unroll
      for (int it = 0; it < 8; ++it) {
        int idx = t + it * 256;
        int r = idx >> 4, q = idx & 15;
        int gr = row0 + r;
        float4 v = make_float4(0.f, 0.f, 0.f, 0.f);
        if (gr < N) v = Av[(size_t)gr * 16 + q];
        *(float4*)&As[r * 68 + ((q ^ (r >> 3)) << 2)] = v;
      }
    }
    __syncthreads();
    const int bsw = tx >> 1;
#pragma unroll 4
    for (int kq = 0; kq < 16; ++kq) {
      float4 b[4];
      const int bq = (kq ^ bsw) << 2;
#pragma unroll
      for (int j = 0; j < 4; ++j)
        b[j] = *(const float4*)&Bs[(tx * 4 + j) * 68 + bq];
      const int aq = (kq ^ ty) << 2;
#pragma unroll
      for (int i = 0; i < 8; ++i) {
        float4 a = *(const float4*)&As[(ty * 8 + i) * 68 + aq];
#pragma unroll
        for (int j = 0; j < 4; ++j) {
          acc[i][j] = fmaf(a.x, b[j].x, acc[i][j]);
          acc[i][j] = fmaf(a.y, b[j].y, acc[i][j]);
          acc[i][j] = fmaf(a.z, b[j].z, acc[i][j]);
          acc[i][j] = fmaf(a.w, b[j].w, acc[i][j]);
        }
      }
    }
  }
  float4 bv = ((const float4*)bias)[tx];
#pragma unroll
  for (int i = 0; i < 8; ++i) {
    int gr = row0 + ty * 8 + i;
    if (gr < N) {
      float4 o;
      o.x = acc[i][0] + bv.x; o.y = acc[i][1] + bv.y;
      o.z = acc[i][2] + bv.z; o.w = acc[i][3] + bv.w;
      if (dorelu) {
        o.x = fmaxf(o.x, 0.f); o.y = fmaxf(o.y, 0.f);
        o.z = fmaxf(o.z, 0.f); o.w = fmaxf(o.w, 0.f);
      }
      ((float4*)Y)[(size_t)gr * 16 + tx] = o;
    }
  }
}

// ---- post linear: Y[N,32] = A @ W^T + b ----
__global__ __launch_bounds__(256) void k_postlin32(
    const float* __restrict__ A, const float* __restrict__ W,
    const float* __restrict__ bias, float* __restrict__ Y, int N) {
  __shared__ float As[128 * 68];
  __shared__ float Bs[32 * 68];
  const int t = threadIdx.x;
  const int tx = t & 7, ty = t >> 3;
  const int row0 = blockIdx.x * 128;

  float acc[4][4];
#pragma unroll
  for (int i = 0; i < 4; ++i)
#pragma unroll
    for (int j = 0; j < 4; ++j) acc[i][j] = 0.0f;

  {
    const float4* Wv = (const float4*)W;
#pragma unroll
    for (int it = 0; it < 2; ++it) {
      int idx = t + it * 256;
      int c = idx >> 4, q = idx & 15;
      float4 v = Wv[idx];
      *(float4*)&Bs[c * 68 + ((q ^ (c >> 3)) << 2)] = v;
    }
  }
  {
    const float4* Av = (const float4*)A;
#pragma unroll
    for (int it = 0; it < 8; ++it) {
      int idx = t + it * 256;
      int r = idx >> 4, q = idx & 15;
      int gr = row0 + r;
      float4 v = make_float4(0.f, 0.f, 0.f, 0.f);
      if (gr < N) v = Av[(size_t)gr * 16 + q];
      *(float4*)&As[r * 68 + ((q ^ (r >> 3)) << 2)] = v;
    }
  }
  __syncthreads();
  const int bsw = tx >> 1;
  const int asw = ty >> 1;
#pragma unroll 4
  for (int kq = 0; kq < 16; ++kq) {
    float4 b[4];
    const int bq = (kq ^ bsw) << 2;
#pragma unroll
    for (int j = 0; j < 4; ++j)
      b[j] = *(const float4*)&Bs[(tx * 4 + j) * 68 + bq];
    const int aq = (kq ^ asw) << 2;
#pragma unroll
    for (int i = 0; i < 4; ++i) {
      float4 a = *(const float4*)&As[(ty * 4 + i) * 68 + aq];
#pragma unroll
      for (int j = 0; j < 4; ++j) {
        acc[i][j] = fmaf(a.x, b[j].x, acc[i][j]);
        acc[i][j] = fmaf(a.y, b[j].y, acc[i][j]);
        acc[i][j] = fmaf(a.z, b[j].z, acc[i][j]);
        acc[i][j] = fmaf(a.w, b[j].w, acc[i][j]);
      }
    }
  }
  float4 bv = ((const float4*)bias)[tx];
#pragma unroll
  for (int i = 0; i < 4; ++i) {
    int gr = row0 + ty * 4 + i;
    if (gr < N) {
      float4 o;
      o.x = acc[i][0] + bv.x; o.y = acc[i][1] + bv.y;
      o.z = acc[i][2] + bv.z; o.w = acc[i][3] + bv.w;
      ((float4*)Y)[(size_t)gr * 8 + tx] = o;
    }
  }
}

extern "C" void kernel_launch(void* const* d_in, const int* in_sizes, int n_in,
                              void* d_out, int out_size, void* d_ws, size_t ws_size,
                              hipStream_t stream) {
  const float* x_user = (const float*)d_in[0];
  const float* x_item = (const float*)d_in[1];
  const int* ei_u2i = (const int*)d_in[2];
  const int* ei_i2u = (const int*)d_in[3];
  const float* pre_w_user = (const float*)d_in[4];
  const float* pre_b_user = (const float*)d_in[5];
  const float* pre_w_item = (const float*)d_in[6];
  const float* pre_b_item = (const float*)d_in[7];
  const float* post_w_user = (const float*)d_in[20];
  const float* post_b_user = (const float*)d_in[21];
  const float* post_w_item = (const float*)d_in[22];
  const float* post_b_item = (const float*)d_in[23];

  const int NU = in_sizes[0] / FDIM;
  const int NI = in_sizes[1] / FDIM;
  const int E = in_sizes[2] / 2;

  // ---- workspace: floats then ints ----
  float* wsf = (float*)d_ws;
  float* h_u = wsf;  wsf += (size_t)NU * FDIM;
  float* h_i = wsf;  wsf += (size_t)NI * FDIM;
  float* x1_u = wsf; wsf += (size_t)NU * FDIM;
  float* x1_i = wsf; wsf += (size_t)NI * FDIM;
  float* msg = wsf;  wsf += (size_t)NU * FDIM;  // max(NU,NI) rows
  int* wsi = (int*)wsf;
  int* off_i = wsi;   wsi += NI + 1;
  int* off_u = wsi;   wsi += NU + 1;
  int* cur_i = wsi;   wsi += NI;    // doubles as cnt_i then cursor_i
  int* cur_u = wsi;   wsi += NU;    // doubles as cnt_u then cursor_u
  int* partials = wsi; wsi += 256;
  int* csr_u2i = wsi; wsi += E;
  int* csr_i2u = wsi; wsi += E;

  const int* u2i_src = ei_u2i;
  const int* u2i_dst = ei_u2i + E;
  const int* i2u_src = ei_i2u;
  const int* i2u_dst = ei_i2u + E;

  const int gE1 = (E + 255) / 256;
  const int tU = (NU + 127) / 128;
  const int tI = (NI + 127) / 128;
  const int bI = (NI + 2047) / 2048;  // scan1 blocks (<=256)
  const int bU = (NU + 2047) / 2048;
  const int gGI = (NI + 3) / 4;       // gather grids
  const int gGU = (NU + 3) / 4;

  // pre linears (independent of CSR build)
  k_gemm64<<<tU, 256, 0, stream>>>(x_user, nullptr, pre_w_user, nullptr,
                                   pre_b_user, 0, 0, h_u, NU);
  k_gemm64<<<tI, 256, 0, stream>>>(x_item, nullptr, pre_w_item, nullptr,
                                   pre_b_item, 0, 0, h_i, NI);

  // ---- CSR build: u2i (dst = items) ----
  hipMemsetAsync(cur_i, 0, (size_t)NI * sizeof(int), stream);
  k_count_deg<<<gE1, 256, 0, stream>>>(u2i_dst, E, cur_i);
  k_scan1<<<bI, 256, 0, stream>>>(cur_i, NI, off_i, partials);
  k_scan2<<<1, 256, 0, stream>>>(partials, bI);
  k_scan3<<<(NI + 255) / 256, 256, 0, stream>>>(off_i, partials, NI, E, cur_i);
  k_fill<<<gE1, 256, 0, stream>>>(u2i_src, u2i_dst, E, cur_i, csr_u2i);

  // ---- CSR build: i2u (dst = users) ----
  hipMemsetAsync(cur_u, 0, (size_t)NU * sizeof(int), stream);
  k_count_deg<<<gE1, 256, 0, stream>>>(i2u_dst, E, cur_u);
  k_scan1<<<bU, 256, 0, stream>>>(cur_u, NU, off_u, partials);
  k_scan2<<<1, 256, 0, stream>>>(partials, bU);
  k_scan3<<<(NU + 255) / 256, 256, 0, stream>>>(off_u, partials, NU, E, cur_u);
  k_fill<<<gE1, 256, 0, stream>>>(i2u_src, i2u_dst, E, cur_u, csr_i2u);

  // ---- layer 1 ----
  k_gather_mean<<<gGI, 256, 0, stream>>>(h_u, off_i, csr_u2i, msg, NI);
  k_gemm64<<<tI, 256, 0, stream>>>(msg, h_i, (const float*)d_in[8],
                                   (const float*)d_in[10], (const float*)d_in[9],
                                   1, 1, x1_i, NI);
  k_gather_mean<<<gGU, 256, 0, stream>>>(h_i, off_u, csr_i2u, msg, NU);
  k_gemm64<<<tU, 256, 0, stream>>>(msg, h_u, (const float*)d_in[11],
                                   (const float*)d_in[13], (const float*)d_in[12],
                                   1, 1, x1_u, NU);

  // ---- layer 2 (outputs overwrite h_i / h_u) ----
  k_gather_mean<<<gGI, 256, 0, stream>>>(x1_u, off_i, csr_u2i, msg, NI);
  k_gemm64<<<tI, 256, 0, stream>>>(msg, x1_i, (const float*)d_in[14],
                                   (const float*)d_in[16], (const float*)d_in[15],
                                   1, 1, h_i, NI);
  k_gather_mean<<<gGU, 256, 0, stream>>>(x1_i, off_u, csr_i2u, msg, NU);
  k_gemm64<<<tU, 256, 0, stream>>>(msg, x1_u, (const float*)d_in[17],
                                   (const float*)d_in[19], (const float*)d_in[18],
                                   1, 1, h_u, NU);

  // post linears -> d_out = [out_u | out_i]
  float* out = (float*)d_out;
  k_postlin32<<<tU, 256, 0, stream>>>(h_u, post_w_user, post_b_user, out, NU);
  k_postlin32<<<tI, 256, 0, stream>>>(h_i, post_w_item, post_b_item,
                                      out + (size_t)NU * 32, NI);
}

// Round 4
// 774.966 us; speedup vs baseline: 6.7990x; 1.2265x over previous
//
#include <hip/hip_runtime.h>

// RGCN: hetero 2-layer GraphConv (mean aggr), MI355X.
// R4: bf16 MFMA for all dense GEMMs (no LDS, direct fragment loads) +
// bf16 intermediates everywhere (halves all activation traffic, incl. the
// random gather reads). CSR build + gather structure kept from R3.
// Verified layouts (learn_hip m89/m91/m120):
//   A-frag: A[m = lane&15][k = (lane>>4)*8 + j], 8 contiguous bf16 per lane
//   B-frag: B[k][n], n = lane&15, k = (lane>>4)*8 + j  -> rows of W (W[n][k])
//   C/D   : col = lane&15, row = (lane>>4)*4 + reg

#define FDIM 64
typedef unsigned short u16;
typedef unsigned int u32;
typedef __bf16 bf16x8 __attribute__((ext_vector_type(8)));
typedef float f32x4 __attribute__((ext_vector_type(4)));

__device__ __forceinline__ u16 f2bf(float x) {  // RNE
  u32 b = __builtin_bit_cast(u32, x);
  b += 0x7FFFu + ((b >> 16) & 1u);
  return (u16)(b >> 16);
}

// ---- weight conversion: 12 arrays fp32 -> bf16, optional +I (skip fold) ----
struct WTab {
  const float* src[12];
  u16* dst[12];
  int rows[12];
  int addI[12];
};
__global__ __launch_bounds__(256) void k_wconv(WTab p) {
  int b = blockIdx.x;
  const float* s = p.src[b];
  u16* d = p.dst[b];
  int n = p.rows[b] * 64;
  int addI = p.addI[b];
  for (int i = threadIdx.x; i < n; i += 256) {
    float v = s[i];
    if (addI && (i >> 6) == (i & 63)) v += 1.0f;
    d[i] = f2bf(v);
  }
}

// ---- CSR build (unchanged from R3) ----
__global__ __launch_bounds__(256) void k_count_deg(const int* __restrict__ dst, int E,
                                                   int* __restrict__ cnt) {
  int i = blockIdx.x * 256 + threadIdx.x;
  if (i < E) atomicAdd(&cnt[dst[i]], 1);
}

__global__ __launch_bounds__(256) void k_scan1(const int* __restrict__ cnt, int n,
                                               int* __restrict__ excl,
                                               int* __restrict__ partials) {
  __shared__ int sd[256];
  int t = threadIdx.x;
  int base = blockIdx.x * 2048 + t * 8;
  int v[8]; int local = 0;
#pragma unroll
  for (int i = 0; i < 8; ++i) {
    int idx = base + i;
    int x = (idx < n) ? cnt[idx] : 0;
    v[i] = x; local += x;
  }
  sd[t] = local; __syncthreads();
  int sum = local;
  for (int off = 1; off < 256; off <<= 1) {
    int x = (t >= off) ? sd[t - off] : 0;
    __syncthreads();
    sum += x; sd[t] = sum;
    __syncthreads();
  }
  if (t == 255) partials[blockIdx.x] = sum;
  int run = sum - local;
#pragma unroll
  for (int i = 0; i < 8; ++i) {
    int idx = base + i;
    if (idx < n) excl[idx] = run;
    run += v[i];
  }
}

__global__ __launch_bounds__(256) void k_scan2(int* __restrict__ partials, int nb) {
  __shared__ int sd[256];
  int t = threadIdx.x;
  int v = (t < nb) ? partials[t] : 0;
  sd[t] = v; __syncthreads();
  int sum = v;
  for (int off = 1; off < 256; off <<= 1) {
    int x = (t >= off) ? sd[t - off] : 0;
    __syncthreads();
    sum += x; sd[t] = sum;
    __syncthreads();
  }
  if (t < nb) partials[t] = sum - v;
}

__global__ __launch_bounds__(256) void k_scan3(int* __restrict__ off,
                                               const int* __restrict__ partials, int n,
                                               int total, int* __restrict__ cursor) {
  int idx = blockIdx.x * 256 + threadIdx.x;
  if (idx < n) {
    int v = off[idx] + partials[idx >> 11];
    off[idx] = v;
    cursor[idx] = v;
  }
  if (idx == 0) off[n] = total;
}

__global__ __launch_bounds__(256) void k_fill(const int* __restrict__ src,
                                              const int* __restrict__ dst, int E,
                                              int* __restrict__ cursor,
                                              int* __restrict__ csr) {
  int e = blockIdx.x * 256 + threadIdx.x;
  if (e < E) {
    int d = dst[e];
    int p = atomicAdd(&cursor[d], 1);
    csr[p] = src[e];
  }
}

// ---- gather-mean over bf16 rows: wave per dst; lane = 32*h + c;
// lane covers features {2c,2c+1} (one u32), halves h process alternate edges ----
__global__ __launch_bounds__(256) void k_gather_mean(const u32* __restrict__ xs,
                                                     const int* __restrict__ off,
                                                     const int* __restrict__ csr,
                                                     u32* __restrict__ msg, int N) {
  int d = blockIdx.x * 4 + (threadIdx.x >> 6);
  if (d >= N) return;
  int lane = threadIdx.x & 63, c = lane & 31, h = lane >> 5;
  int beg = off[d], end = off[d + 1];
  float ax0 = 0, ay0 = 0, ax1 = 0, ay1 = 0, ax2 = 0, ay2 = 0, ax3 = 0, ay3 = 0;
  int j = beg + h;
  for (; j + 6 < end; j += 8) {
    int s0 = csr[j], s1 = csr[j + 2], s2 = csr[j + 4], s3 = csr[j + 6];
    u32 p0 = xs[(size_t)s0 * 32 + c];
    u32 p1 = xs[(size_t)s1 * 32 + c];
    u32 p2 = xs[(size_t)s2 * 32 + c];
    u32 p3 = xs[(size_t)s3 * 32 + c];
    ax0 += __builtin_bit_cast(float, p0 << 16); ay0 += __builtin_bit_cast(float, p0 & 0xffff0000u);
    ax1 += __builtin_bit_cast(float, p1 << 16); ay1 += __builtin_bit_cast(float, p1 & 0xffff0000u);
    ax2 += __builtin_bit_cast(float, p2 << 16); ay2 += __builtin_bit_cast(float, p2 & 0xffff0000u);
    ax3 += __builtin_bit_cast(float, p3 << 16); ay3 += __builtin_bit_cast(float, p3 & 0xffff0000u);
  }
  for (; j < end; j += 2) {
    u32 p = xs[(size_t)csr[j] * 32 + c];
    ax0 += __builtin_bit_cast(float, p << 16);
    ay0 += __builtin_bit_cast(float, p & 0xffff0000u);
  }
  float ax = (ax0 + ax1) + (ax2 + ax3);
  float ay = (ay0 + ay1) + (ay2 + ay3);
  ax += __shfl_xor(ax, 32, 64);
  ay += __shfl_xor(ay, 32, 64);
  if (h == 0) {
    float s = 1.0f / fmaxf((float)(end - beg), 1.0f);
    u32 o = (u32)f2bf(ax * s) | ((u32)f2bf(ay * s) << 16);
    msg[(size_t)d * 32 + c] = o;
  }
}

// ---- MFMA GEMM: Y[N,64](bf16) = act( A1 @ W1^T [+ A2 @ W2^T] + bias )
// 128-row tile, 4 waves, wave = 32 rows x 64 cols, K=64 per half. No LDS. ----
__global__ __launch_bounds__(256) void k_mfma_gemm64(
    const void* __restrict__ A1, int a1_fp32, const u16* __restrict__ A2,
    const u16* __restrict__ W1, const u16* __restrict__ W2,
    const float* __restrict__ bias, int dorelu, u16* __restrict__ Y, int N) {
  const int t = threadIdx.x;
  const int w = t >> 6, lane = t & 63;
  const int c = lane & 15, q = lane >> 4;
  const int row0 = blockIdx.x * 128 + w * 32;

  bf16x8 zf;
#pragma unroll
  for (int i = 0; i < 8; ++i) zf[i] = (__bf16)0.0f;

  f32x4 acc[2][4];
#pragma unroll
  for (int ms = 0; ms < 2; ++ms)
#pragma unroll
    for (int n = 0; n < 4; ++n) acc[ms][n] = f32x4{0.f, 0.f, 0.f, 0.f};

  const int nh = (A2 != nullptr) ? 2 : 1;
  for (int h = 0; h < nh; ++h) {
    const u16* W = h ? W2 : W1;
    bf16x8 bfr[4][2];
#pragma unroll
    for (int n = 0; n < 4; ++n)
#pragma unroll
      for (int kc = 0; kc < 2; ++kc)
        bfr[n][kc] = *(const bf16x8*)(W + (n * 16 + c) * 64 + kc * 32 + q * 8);
    bf16x8 afr[2][2];
#pragma unroll
    for (int ms = 0; ms < 2; ++ms) {
      int row = row0 + ms * 16 + c;
      bool ok = row < N;
#pragma unroll
      for (int kc = 0; kc < 2; ++kc) {
        if (h == 0 && a1_fp32) {
          bf16x8 v = zf;
          if (ok) {
            const float* Af = (const float*)A1 + (size_t)row * 64 + kc * 32 + q * 8;
            float4 u0 = *(const float4*)Af;
            float4 u1 = *(const float4*)(Af + 4);
            v[0] = (__bf16)u0.x; v[1] = (__bf16)u0.y; v[2] = (__bf16)u0.z; v[3] = (__bf16)u0.w;
            v[4] = (__bf16)u1.x; v[5] = (__bf16)u1.y; v[6] = (__bf16)u1.z; v[7] = (__bf16)u1.w;
          }
          afr[ms][kc] = v;
        } else {
          const u16* Ab = (h == 0) ? (const u16*)A1 : A2;
          afr[ms][kc] = ok ? *(const bf16x8*)(Ab + (size_t)row * 64 + kc * 32 + q * 8) : zf;
        }
      }
    }
#pragma unroll
    for (int n = 0; n < 4; ++n)
#pragma unroll
      for (int ms = 0; ms < 2; ++ms)
#pragma unroll
        for (int kc = 0; kc < 2; ++kc)
          acc[ms][n] = __builtin_amdgcn_mfma_f32_16x16x32_bf16(afr[ms][kc], bfr[n][kc],
                                                               acc[ms][n], 0, 0, 0);
  }
  // epilogue: +bias, relu, bf16 store. C/D: col = c, row = q*4 + reg.
#pragma unroll
  for (int n = 0; n < 4; ++n) {
    float bv = bias[n * 16 + c];
#pragma unroll
    for (int ms = 0; ms < 2; ++ms) {
#pragma unroll
      for (int r = 0; r < 4; ++r) {
        int row = row0 + ms * 16 + q * 4 + r;
        if (row < N) {
          float v = acc[ms][n][r] + bv;
          if (dorelu) v = fmaxf(v, 0.f);
          Y[(size_t)row * 64 + n * 16 + c] = f2bf(v);
        }
      }
    }
  }
}

// ---- MFMA post linear: Y[N,32](fp32) = A(bf16) @ W[32,64]^T + bias ----
__global__ __launch_bounds__(256) void k_mfma_postlin(
    const u16* __restrict__ A, const u16* __restrict__ W,
    const float* __restrict__ bias, float* __restrict__ Y, int N) {
  const int t = threadIdx.x;
  const int w = t >> 6, lane = t & 63;
  const int c = lane & 15, q = lane >> 4;
  const int row0 = blockIdx.x * 128 + w * 32;

  bf16x8 zf;
#pragma unroll
  for (int i = 0; i < 8; ++i) zf[i] = (__bf16)0.0f;

  f32x4 acc[2][2];
#pragma unroll
  for (int ms = 0; ms < 2; ++ms)
#pragma unroll
    for (int n = 0; n < 2; ++n) acc[ms][n] = f32x4{0.f, 0.f, 0.f, 0.f};

  bf16x8 bfr[2][2];
#pragma unroll
  for (int n = 0; n < 2; ++n)
#pragma unroll
    for (int kc = 0; kc < 2; ++kc)
      bfr[n][kc] = *(const bf16x8*)(W + (n * 16 + c) * 64 + kc * 32 + q * 8);
  bf16x8 afr[2][2];
#pragma unroll
  for (int ms = 0; ms < 2; ++ms) {
    int row = row0 + ms * 16 + c;
    bool ok = row < N;
#pragma unroll
    for (int kc = 0; kc < 2; ++kc)
      afr[ms][kc] = ok ? *(const bf16x8*)(A + (size_t)row * 64 + kc * 32 + q * 8) : zf;
  }
#pragma unroll
  for (int n = 0; n < 2; ++n)
#pragma unroll
    for (int ms = 0; ms < 2; ++ms)
#pragma unroll
      for (int kc = 0; kc < 2; ++kc)
        acc[ms][n] = __builtin_amdgcn_mfma_f32_16x16x32_bf16(afr[ms][kc], bfr[n][kc],
                                                             acc[ms][n], 0, 0, 0);
#pragma unroll
  for (int n = 0; n < 2; ++n) {
    float bv = bias[n * 16 + c];
#pragma unroll
    for (int ms = 0; ms < 2; ++ms) {
#pragma unroll
      for (int r = 0; r < 4; ++r) {
        int row = row0 + ms * 16 + q * 4 + r;
        if (row < N) Y[(size_t)row * 32 + n * 16 + c] = acc[ms][n][r] + bv;
      }
    }
  }
}

extern "C" void kernel_launch(void* const* d_in, const int* in_sizes, int n_in,
                              void* d_out, int out_size, void* d_ws, size_t ws_size,
                              hipStream_t stream) {
  const float* x_user = (const float*)d_in[0];
  const float* x_item = (const float*)d_in[1];
  const int* ei_u2i = (const int*)d_in[2];
  const int* ei_i2u = (const int*)d_in[3];

  const int NU = in_sizes[0] / FDIM;
  const int NI = in_sizes[1] / FDIM;
  const int E = in_sizes[2] / 2;

  // ---- workspace: bf16 activations, bf16 weights, then ints ----
  u16* wsu = (u16*)d_ws;
  u16* h_u = wsu;  wsu += (size_t)NU * FDIM;
  u16* h_i = wsu;  wsu += (size_t)NI * FDIM;
  u16* x1_u = wsu; wsu += (size_t)NU * FDIM;
  u16* x1_i = wsu; wsu += (size_t)NI * FDIM;
  u16* msg = wsu;  wsu += (size_t)NU * FDIM;  // max(NU,NI) rows
  u16* wb = wsu;   wsu += 12 * 4096;          // 12 converted weight mats
  int* wsi = (int*)wsu;
  int* off_i = wsi;   wsi += NI + 1;
  int* off_u = wsi;   wsi += NU + 1;
  int* cur_i = wsi;   wsi += NI;
  int* cur_u = wsi;   wsi += NU;
  int* partials = wsi; wsi += 256;
  int* csr_u2i = wsi; wsi += E;
  int* csr_i2u = wsi; wsi += E;

  const int* u2i_src = ei_u2i;
  const int* u2i_dst = ei_u2i + E;
  const int* i2u_src = ei_i2u;
  const int* i2u_dst = ei_i2u + E;

  const int gE1 = (E + 255) / 256;
  const int tU = (NU + 127) / 128;
  const int tI = (NI + 127) / 128;
  const int bI = (NI + 2047) / 2048;
  const int bU = (NU + 2047) / 2048;
  const int gGI = (NI + 3) / 4;
  const int gGU = (NU + 3) / 4;

  // ---- weight conversion (once per launch; skip folded: wroot + I) ----
  WTab tab;
  const int widx[12] = {4, 6, 8, 10, 11, 13, 14, 16, 17, 19, 20, 22};
  const int addI[12] = {0, 0, 0, 1, 0, 1, 0, 1, 0, 1, 0, 0};
  const int rows_[12] = {64, 64, 64, 64, 64, 64, 64, 64, 64, 64, 32, 32};
  for (int i = 0; i < 12; ++i) {
    tab.src[i] = (const float*)d_in[widx[i]];
    tab.dst[i] = wb + i * 4096;
    tab.rows[i] = rows_[i];
    tab.addI[i] = addI[i];
  }
  k_wconv<<<12, 256, 0, stream>>>(tab);

  // ---- CSR build: u2i (dst = items) ----
  hipMemsetAsync(cur_i, 0, (size_t)NI * sizeof(int), stream);
  k_count_deg<<<gE1, 256, 0, stream>>>(u2i_dst, E, cur_i);
  k_scan1<<<bI, 256, 0, stream>>>(cur_i, NI, off_i, partials);
  k_scan2<<<1, 256, 0, stream>>>(partials, bI);
  k_scan3<<<(NI + 255) / 256, 256, 0, stream>>>(off_i, partials, NI, E, cur_i);
  k_fill<<<gE1, 256, 0, stream>>>(u2i_src, u2i_dst, E, cur_i, csr_u2i);
  // ---- CSR build: i2u (dst = users) ----
  hipMemsetAsync(cur_u, 0, (size_t)NU * sizeof(int), stream);
  k_count_deg<<<gE1, 256, 0, stream>>>(i2u_dst, E, cur_u);
  k_scan1<<<bU, 256, 0, stream>>>(cur_u, NU, off_u, partials);
  k_scan2<<<1, 256, 0, stream>>>(partials, bU);
  k_scan3<<<(NU + 255) / 256, 256, 0, stream>>>(off_u, partials, NU, E, cur_u);
  k_fill<<<gE1, 256, 0, stream>>>(i2u_src, i2u_dst, E, cur_u, csr_i2u);

  // ---- pre linears: fp32 x -> bf16 h ----
  k_mfma_gemm64<<<tU, 256, 0, stream>>>(x_user, 1, nullptr, wb + 0 * 4096, nullptr,
                                        (const float*)d_in[5], 0, h_u, NU);
  k_mfma_gemm64<<<tI, 256, 0, stream>>>(x_item, 1, nullptr, wb + 1 * 4096, nullptr,
                                        (const float*)d_in[7], 0, h_i, NI);

  // ---- layer 1 ----
  k_gather_mean<<<gGI, 256, 0, stream>>>((const u32*)h_u, off_i, csr_u2i, (u32*)msg, NI);
  k_mfma_gemm64<<<tI, 256, 0, stream>>>(msg, 0, h_i, wb + 2 * 4096, wb + 3 * 4096,
                                        (const float*)d_in[9], 1, x1_i, NI);
  k_gather_mean<<<gGU, 256, 0, stream>>>((const u32*)h_i, off_u, csr_i2u, (u32*)msg, NU);
  k_mfma_gemm64<<<tU, 256, 0, stream>>>(msg, 0, h_u, wb + 4 * 4096, wb + 5 * 4096,
                                        (const float*)d_in[12], 1, x1_u, NU);

  // ---- layer 2 (outputs overwrite h_i / h_u) ----
  k_gather_mean<<<gGI, 256, 0, stream>>>((const u32*)x1_u, off_i, csr_u2i, (u32*)msg, NI);
  k_mfma_gemm64<<<tI, 256, 0, stream>>>(msg, 0, x1_i, wb + 6 * 4096, wb + 7 * 4096,
                                        (const float*)d_in[15], 1, h_i, NI);
  k_gather_mean<<<gGU, 256, 0, stream>>>((const u32*)x1_i, off_u, csr_i2u, (u32*)msg, NU);
  k_mfma_gemm64<<<tU, 256, 0, stream>>>(msg, 0, x1_u, wb + 8 * 4096, wb + 9 * 4096,
                                        (const float*)d_in[18], 1, h_u, NU);

  // ---- post linears -> fp32 d_out = [out_u | out_i] ----
  float* out = (float*)d_out;
  k_mfma_postlin<<<tU, 256, 0, stream>>>(h_u, wb + 10 * 4096, (const float*)d_in[21], out, NU);
  k_mfma_postlin<<<tI, 256, 0, stream>>>(h_i, wb + 11 * 4096, (const float*)d_in[23],
                                         out + (size_t)NU * 32, NI);
}

// Round 5
// 690.716 us; speedup vs baseline: 7.6284x; 1.1220x over previous
//
#include <hip/hip_runtime.h>

// RGCN: hetero 2-layer GraphConv (mean aggr), MI355X.
// R5: (a) two-pass bucketed CSR fill -- Pass A bins edges by 256/512-dst
// buckets (LDS histogram + bulk reservation), Pass B places each bucket's
// edges via LDS cursors + LDS-staged csr region, written out coalesced.
// Kills the 16x write amplification of the R4 random scatter (69MB -> ~13MB).
// (b) vectorized gather: uint4 row loads (8 edges/wave/instr), csr indices
// pre-loaded 64-at-a-time + __shfl distribution, butterfly slot reduction.
// Dense MFMA GEMMs unchanged from R4.

#define FDIM 64
typedef unsigned short u16;
typedef unsigned int u32;
typedef __bf16 bf16x8 __attribute__((ext_vector_type(8)));
typedef float f32x4 __attribute__((ext_vector_type(4)));

__device__ __forceinline__ u16 f2bf(float x) {  // RNE
  u32 b = __builtin_bit_cast(u32, x);
  b += 0x7FFFu + ((b >> 16) & 1u);
  return (u16)(b >> 16);
}
__device__ __forceinline__ float blo(u32 p) { return __builtin_bit_cast(float, p << 16); }
__device__ __forceinline__ float bhi(u32 p) { return __builtin_bit_cast(float, p & 0xffff0000u); }

// ---- weight conversion: 12 arrays fp32 -> bf16, optional +I (skip fold) ----
struct WTab {
  const float* src[12];
  u16* dst[12];
  int rows[12];
  int addI[12];
};
__global__ __launch_bounds__(256) void k_wconv(WTab p) {
  int b = blockIdx.x;
  const float* s = p.src[b];
  u16* d = p.dst[b];
  int n = p.rows[b] * 64;
  int addI = p.addI[b];
  for (int i = threadIdx.x; i < n; i += 256) {
    float v = s[i];
    if (addI && (i >> 6) == (i & 63)) v += 1.0f;
    d[i] = f2bf(v);
  }
}

// ---- degree count ----
__global__ __launch_bounds__(256) void k_count_deg(const int* __restrict__ dst, int E,
                                                   int* __restrict__ cnt) {
  int i = blockIdx.x * 256 + threadIdx.x;
  if (i < E) atomicAdd(&cnt[dst[i]], 1);
}

__global__ __launch_bounds__(256) void k_scan1(const int* __restrict__ cnt, int n,
                                               int* __restrict__ excl,
                                               int* __restrict__ partials) {
  __shared__ int sd[256];
  int t = threadIdx.x;
  int base = blockIdx.x * 2048 + t * 8;
  int v[8]; int local = 0;
#pragma unroll
  for (int i = 0; i < 8; ++i) {
    int idx = base + i;
    int x = (idx < n) ? cnt[idx] : 0;
    v[i] = x; local += x;
  }
  sd[t] = local; __syncthreads();
  int sum = local;
  for (int off = 1; off < 256; off <<= 1) {
    int x = (t >= off) ? sd[t - off] : 0;
    __syncthreads();
    sum += x; sd[t] = sum;
    __syncthreads();
  }
  if (t == 255) partials[blockIdx.x] = sum;
  int run = sum - local;
#pragma unroll
  for (int i = 0; i < 8; ++i) {
    int idx = base + i;
    if (idx < n) excl[idx] = run;
    run += v[i];
  }
}

__global__ __launch_bounds__(256) void k_scan2(int* __restrict__ partials, int nb) {
  __shared__ int sd[256];
  int t = threadIdx.x;
  int v = (t < nb) ? partials[t] : 0;
  sd[t] = v; __syncthreads();
  int sum = v;
  for (int off = 1; off < 256; off <<= 1) {
    int x = (t >= off) ? sd[t - off] : 0;
    __syncthreads();
    sum += x; sd[t] = sum;
    __syncthreads();
  }
  if (t < nb) partials[t] = sum - v;
}

// off[] finalize + per-dst cursor copy (fallback) + bucket-base cursors
__global__ __launch_bounds__(256) void k_scan3(int* __restrict__ off,
                                               const int* __restrict__ partials, int n,
                                               int total, int* __restrict__ cursor,
                                               int shift, int* __restrict__ gcurb) {
  int idx = blockIdx.x * 256 + threadIdx.x;
  if (idx < n) {
    int v = off[idx] + partials[idx >> 11];
    off[idx] = v;
    cursor[idx] = v;
    if ((idx & ((1 << shift) - 1)) == 0) gcurb[idx >> shift] = v;
  }
  if (idx == 0) off[n] = total;
}

// ---- Pass A: bin edges into bucket-grouped (src,dst) pairs ----
#define PA_C 4096
__global__ __launch_bounds__(256) void k_binA(const int* __restrict__ src,
                                              const int* __restrict__ dst, int E,
                                              int shift, int nb,
                                              int* __restrict__ gcurb,
                                              int2* __restrict__ aux) {
  __shared__ int cnt[512];
  __shared__ int base[512];
  int t = threadIdx.x;
  int e0 = blockIdx.x * PA_C;
  int n = min(PA_C, E - e0);
  for (int b = t; b < nb; b += 256) cnt[b] = 0;
  __syncthreads();
  int ls[16], ld[16];
#pragma unroll
  for (int i = 0; i < 16; ++i) {
    int r = t + i * 256;
    if (r < n) {
      ls[i] = src[e0 + r];
      ld[i] = dst[e0 + r];
      atomicAdd(&cnt[ld[i] >> shift], 1);
    }
  }
  __syncthreads();
  for (int b = t; b < nb; b += 256) {
    int c = cnt[b];
    base[b] = c ? atomicAdd(&gcurb[b], c) : 0;
  }
  __syncthreads();
  for (int b = t; b < nb; b += 256) cnt[b] = 0;
  __syncthreads();
#pragma unroll
  for (int i = 0; i < 16; ++i) {
    int r = t + i * 256;
    if (r < n) {
      int b = ld[i] >> shift;
      int p = base[b] + atomicAdd(&cnt[b], 1);
      aux[p] = make_int2(ls[i], ld[i]);
    }
  }
}

// ---- Pass B: one block per bucket; LDS cursors + LDS-staged csr region ----
__global__ __launch_bounds__(256) void k_binB(const int2* __restrict__ aux,
                                              const int* __restrict__ off,
                                              int shift, int N,
                                              int* __restrict__ cur,
                                              int* __restrict__ csr) {
  __shared__ int stage[4096];
  __shared__ int lcur[512];
  int b = blockIdx.x;
  int d0 = b << shift;
  int d1 = min(d0 + (1 << shift), N);
  int r0 = off[d0], r1 = off[d1];
  int RS = r1 - r0;
  int t = threadIdx.x;
  if (RS <= 4096) {
    for (int i = t; i < d1 - d0; i += 256) lcur[i] = off[d0 + i] - r0;
    __syncthreads();
    for (int i = t; i < RS; i += 256) {
      int2 p = aux[r0 + i];
      int pos = atomicAdd(&lcur[p.y - d0], 1);
      stage[pos] = p.x;
    }
    __syncthreads();
    for (int i = t; i < RS; i += 256) csr[r0 + i] = stage[i];
  } else {  // statistical-overflow fallback (never expected at these sizes)
    for (int i = t; i < RS; i += 256) {
      int2 p = aux[r0 + i];
      int pos = atomicAdd(&cur[p.y], 1);
      csr[pos] = p.x;
    }
  }
}

// ---- gather-mean, vectorized: wave per dst; lane = slot*8 + c;
// slot handles every-8th edge, c = 16B chunk of the 128B row ----
__global__ __launch_bounds__(256) void k_gather_mean(const uint4* __restrict__ xs,
                                                     const int* __restrict__ off,
                                                     const int* __restrict__ csr,
                                                     uint4* __restrict__ msg, int N) {
  int d = blockIdx.x * 4 + (threadIdx.x >> 6);
  if (d >= N) return;
  int lane = threadIdx.x & 63;
  int slot = lane >> 3, c = lane & 7;
  int beg = off[d], end = off[d + 1];
  int deg = end - beg;
  float a[8] = {0.f, 0.f, 0.f, 0.f, 0.f, 0.f, 0.f, 0.f};
  for (int j0 = beg; j0 < end; j0 += 64) {
    int idx = j0 + lane;
    int myS = (idx < end) ? csr[idx] : -1;
#pragma unroll
    for (int it = 0; it < 8; ++it) {
      if (j0 + it * 8 < end) {  // wave-uniform
        int s = __shfl(myS, it * 8 + slot, 64);
        if (s >= 0) {
          uint4 p = xs[(size_t)s * 8 + c];
          a[0] += blo(p.x); a[1] += bhi(p.x);
          a[2] += blo(p.y); a[3] += bhi(p.y);
          a[4] += blo(p.z); a[5] += bhi(p.z);
          a[6] += blo(p.w); a[7] += bhi(p.w);
        }
      }
    }
  }
#pragma unroll
  for (int m = 8; m <= 32; m <<= 1)
#pragma unroll
    for (int k = 0; k < 8; ++k) a[k] += __shfl_xor(a[k], m, 64);
  if (slot == 0) {
    float sc = 1.0f / fmaxf((float)deg, 1.0f);
    uint4 o;
    o.x = (u32)f2bf(a[0] * sc) | ((u32)f2bf(a[1] * sc) << 16);
    o.y = (u32)f2bf(a[2] * sc) | ((u32)f2bf(a[3] * sc) << 16);
    o.z = (u32)f2bf(a[4] * sc) | ((u32)f2bf(a[5] * sc) << 16);
    o.w = (u32)f2bf(a[6] * sc) | ((u32)f2bf(a[7] * sc) << 16);
    msg[(size_t)d * 8 + c] = o;
  }
}

// ---- MFMA GEMM: Y[N,64](bf16) = act( A1 @ W1^T [+ A2 @ W2^T] + bias ) ----
__global__ __launch_bounds__(256) void k_mfma_gemm64(
    const void* __restrict__ A1, int a1_fp32, const u16* __restrict__ A2,
    const u16* __restrict__ W1, const u16* __restrict__ W2,
    const float* __restrict__ bias, int dorelu, u16* __restrict__ Y, int N) {
  const int t = threadIdx.x;
  const int w = t >> 6, lane = t & 63;
  const int c = lane & 15, q = lane >> 4;
  const int row0 = blockIdx.x * 128 + w * 32;

  bf16x8 zf;
#pragma unroll
  for (int i = 0; i < 8; ++i) zf[i] = (__bf16)0.0f;

  f32x4 acc[2][4];
#pragma unroll
  for (int ms = 0; ms < 2; ++ms)
#pragma unroll
    for (int n = 0; n < 4; ++n) acc[ms][n] = f32x4{0.f, 0.f, 0.f, 0.f};

  const int nh = (A2 != nullptr) ? 2 : 1;
  for (int h = 0; h < nh; ++h) {
    const u16* W = h ? W2 : W1;
    bf16x8 bfr[4][2];
#pragma unroll
    for (int n = 0; n < 4; ++n)
#pragma unroll
      for (int kc = 0; kc < 2; ++kc)
        bfr[n][kc] = *(const bf16x8*)(W + (n * 16 + c) * 64 + kc * 32 + q * 8);
    bf16x8 afr[2][2];
#pragma unroll
    for (int ms = 0; ms < 2; ++ms) {
      int row = row0 + ms * 16 + c;
      bool ok = row < N;
#pragma unroll
      for (int kc = 0; kc < 2; ++kc) {
        if (h == 0 && a1_fp32) {
          bf16x8 v = zf;
          if (ok) {
            const float* Af = (const float*)A1 + (size_t)row * 64 + kc * 32 + q * 8;
            float4 u0 = *(const float4*)Af;
            float4 u1 = *(const float4*)(Af + 4);
            v[0] = (__bf16)u0.x; v[1] = (__bf16)u0.y; v[2] = (__bf16)u0.z; v[3] = (__bf16)u0.w;
            v[4] = (__bf16)u1.x; v[5] = (__bf16)u1.y; v[6] = (__bf16)u1.z; v[7] = (__bf16)u1.w;
          }
          afr[ms][kc] = v;
        } else {
          const u16* Ab = (h == 0) ? (const u16*)A1 : A2;
          afr[ms][kc] = ok ? *(const bf16x8*)(Ab + (size_t)row * 64 + kc * 32 + q * 8) : zf;
        }
      }
    }
#pragma unroll
    for (int n = 0; n < 4; ++n)
#pragma unroll
      for (int ms = 0; ms < 2; ++ms)
#pragma unroll
        for (int kc = 0; kc < 2; ++kc)
          acc[ms][n] = __builtin_amdgcn_mfma_f32_16x16x32_bf16(afr[ms][kc], bfr[n][kc],
                                                               acc[ms][n], 0, 0, 0);
  }
#pragma unroll
  for (int n = 0; n < 4; ++n) {
    float bv = bias[n * 16 + c];
#pragma unroll
    for (int ms = 0; ms < 2; ++ms) {
#pragma unroll
      for (int r = 0; r < 4; ++r) {
        int row = row0 + ms * 16 + q * 4 + r;
        if (row < N) {
          float v = acc[ms][n][r] + bv;
          if (dorelu) v = fmaxf(v, 0.f);
          Y[(size_t)row * 64 + n * 16 + c] = f2bf(v);
        }
      }
    }
  }
}

// ---- MFMA post linear: Y[N,32](fp32) = A(bf16) @ W[32,64]^T + bias ----
__global__ __launch_bounds__(256) void k_mfma_postlin(
    const u16* __restrict__ A, const u16* __restrict__ W,
    const float* __restrict__ bias, float* __restrict__ Y, int N) {
  const int t = threadIdx.x;
  const int w = t >> 6, lane = t & 63;
  const int c = lane & 15, q = lane >> 4;
  const int row0 = blockIdx.x * 128 + w * 32;

  bf16x8 zf;
#pragma unroll
  for (int i = 0; i < 8; ++i) zf[i] = (__bf16)0.0f;

  f32x4 acc[2][2];
#pragma unroll
  for (int ms = 0; ms < 2; ++ms)
#pragma unroll
    for (int n = 0; n < 2; ++n) acc[ms][n] = f32x4{0.f, 0.f, 0.f, 0.f};

  bf16x8 bfr[2][2];
#pragma unroll
  for (int n = 0; n < 2; ++n)
#pragma unroll
    for (int kc = 0; kc < 2; ++kc)
      bfr[n][kc] = *(const bf16x8*)(W + (n * 16 + c) * 64 + kc * 32 + q * 8);
  bf16x8 afr[2][2];
#pragma unroll
  for (int ms = 0; ms < 2; ++ms) {
    int row = row0 + ms * 16 + c;
    bool ok = row < N;
#pragma unroll
    for (int kc = 0; kc < 2; ++kc)
      afr[ms][kc] = ok ? *(const bf16x8*)(A + (size_t)row * 64 + kc * 32 + q * 8) : zf;
  }
#pragma unroll
  for (int n = 0; n < 2; ++n)
#pragma unroll
    for (int ms = 0; ms < 2; ++ms)
#pragma unroll
      for (int kc = 0; kc < 2; ++kc)
        acc[ms][n] = __builtin_amdgcn_mfma_f32_16x16x32_bf16(afr[ms][kc], bfr[n][kc],
                                                             acc[ms][n], 0, 0, 0);
#pragma unroll
  for (int n = 0; n < 2; ++n) {
    float bv = bias[n * 16 + c];
#pragma unroll
    for (int ms = 0; ms < 2; ++ms) {
#pragma unroll
      for (int r = 0; r < 4; ++r) {
        int row = row0 + ms * 16 + q * 4 + r;
        if (row < N) Y[(size_t)row * 32 + n * 16 + c] = acc[ms][n][r] + bv;
      }
    }
  }
}

extern "C" void kernel_launch(void* const* d_in, const int* in_sizes, int n_in,
                              void* d_out, int out_size, void* d_ws, size_t ws_size,
                              hipStream_t stream) {
  const float* x_user = (const float*)d_in[0];
  const float* x_item = (const float*)d_in[1];
  const int* ei_u2i = (const int*)d_in[2];
  const int* ei_i2u = (const int*)d_in[3];

  const int NU = in_sizes[0] / FDIM;
  const int NI = in_sizes[1] / FDIM;
  const int E = in_sizes[2] / 2;

  // ---- workspace ----
  u16* wsu = (u16*)d_ws;
  u16* h_u = wsu;  wsu += (size_t)NU * FDIM;
  u16* h_i = wsu;  wsu += (size_t)NI * FDIM;
  u16* x1_u = wsu; wsu += (size_t)NU * FDIM;
  u16* x1_i = wsu; wsu += (size_t)NI * FDIM;
  u16* msg = wsu;  wsu += (size_t)NU * FDIM;  // max(NU,NI) rows
  u16* wb = wsu;   wsu += 12 * 4096;
  int2* aux = (int2*)wsu;                      // E pairs (8B-aligned: offset %128==0)
  int* wsi = (int*)(aux + E);
  int* off_i = wsi;    wsi += NI + 1;
  int* off_u = wsi;    wsi += NU + 1;
  int* cur_i = wsi;    wsi += NI;
  int* cur_u = wsi;    wsi += NU;
  int* partials = wsi; wsi += 256;
  int* gcurb_i = wsi;  wsi += 512;
  int* gcurb_u = wsi;  wsi += 512;
  int* csr_u2i = wsi;  wsi += E;
  int* csr_i2u = wsi;  wsi += E;

  const int* u2i_src = ei_u2i;
  const int* u2i_dst = ei_u2i + E;
  const int* i2u_src = ei_i2u;
  const int* i2u_dst = ei_i2u + E;

  const int gE1 = (E + 255) / 256;
  const int gA = (E + PA_C - 1) / PA_C;
  const int tU = (NU + 127) / 128;
  const int tI = (NI + 127) / 128;
  const int bI = (NI + 2047) / 2048;
  const int bU = (NU + 2047) / 2048;
  const int gGI = (NI + 3) / 4;
  const int gGU = (NU + 3) / 4;
  const int SH_I = 8, SH_U = 9;                 // bucket = 256 dsts (items) / 512 (users)
  const int nbI = (NI + (1 << SH_I) - 1) >> SH_I;  // 391
  const int nbU = (NU + (1 << SH_U) - 1) >> SH_U;  // 391

  // ---- weight conversion (skip folded: wroot + I) ----
  WTab tab;
  const int widx[12] = {4, 6, 8, 10, 11, 13, 14, 16, 17, 19, 20, 22};
  const int addI[12] = {0, 0, 0, 1, 0, 1, 0, 1, 0, 1, 0, 0};
  const int rows_[12] = {64, 64, 64, 64, 64, 64, 64, 64, 64, 64, 32, 32};
  for (int i = 0; i < 12; ++i) {
    tab.src[i] = (const float*)d_in[widx[i]];
    tab.dst[i] = wb + i * 4096;
    tab.rows[i] = rows_[i];
    tab.addI[i] = addI[i];
  }
  k_wconv<<<12, 256, 0, stream>>>(tab);

  // ---- pre linears: fp32 x -> bf16 h ----
  k_mfma_gemm64<<<tU, 256, 0, stream>>>(x_user, 1, nullptr, wb + 0 * 4096, nullptr,
                                        (const float*)d_in[5], 0, h_u, NU);
  k_mfma_gemm64<<<tI, 256, 0, stream>>>(x_item, 1, nullptr, wb + 1 * 4096, nullptr,
                                        (const float*)d_in[7], 0, h_i, NI);

  // ---- CSR build: u2i (dst = items) ----
  hipMemsetAsync(cur_i, 0, (size_t)NI * sizeof(int), stream);
  k_count_deg<<<gE1, 256, 0, stream>>>(u2i_dst, E, cur_i);
  k_scan1<<<bI, 256, 0, stream>>>(cur_i, NI, off_i, partials);
  k_scan2<<<1, 256, 0, stream>>>(partials, bI);
  k_scan3<<<(NI + 255) / 256, 256, 0, stream>>>(off_i, partials, NI, E, cur_i, SH_I, gcurb_i);
  k_binA<<<gA, 256, 0, stream>>>(u2i_src, u2i_dst, E, SH_I, nbI, gcurb_i, aux);
  k_binB<<<nbI, 256, 0, stream>>>(aux, off_i, SH_I, NI, cur_i, csr_u2i);
  // ---- CSR build: i2u (dst = users); aux reused (stream-ordered) ----
  hipMemsetAsync(cur_u, 0, (size_t)NU * sizeof(int), stream);
  k_count_deg<<<gE1, 256, 0, stream>>>(i2u_dst, E, cur_u);
  k_scan1<<<bU, 256, 0, stream>>>(cur_u, NU, off_u, partials);
  k_scan2<<<1, 256, 0, stream>>>(partials, bU);
  k_scan3<<<(NU + 255) / 256, 256, 0, stream>>>(off_u, partials, NU, E, cur_u, SH_U, gcurb_u);
  k_binA<<<gA, 256, 0, stream>>>(i2u_src, i2u_dst, E, SH_U, nbU, gcurb_u, aux);
  k_binB<<<nbU, 256, 0, stream>>>(aux, off_u, SH_U, NU, cur_u, csr_i2u);

  // ---- layer 1 ----
  k_gather_mean<<<gGI, 256, 0, stream>>>((const uint4*)h_u, off_i, csr_u2i, (uint4*)msg, NI);
  k_mfma_gemm64<<<tI, 256, 0, stream>>>(msg, 0, h_i, wb + 2 * 4096, wb + 3 * 4096,
                                        (const float*)d_in[9], 1, x1_i, NI);
  k_gather_mean<<<gGU, 256, 0, stream>>>((const uint4*)h_i, off_u, csr_i2u, (uint4*)msg, NU);
  k_mfma_gemm64<<<tU, 256, 0, stream>>>(msg, 0, h_u, wb + 4 * 4096, wb + 5 * 4096,
                                        (const float*)d_in[12], 1, x1_u, NU);

  // ---- layer 2 (outputs overwrite h_i / h_u) ----
  k_gather_mean<<<gGI, 256, 0, stream>>>((const uint4*)x1_u, off_i, csr_u2i, (uint4*)msg, NI);
  k_mfma_gemm64<<<tI, 256, 0, stream>>>(msg, 0, x1_i, wb + 6 * 4096, wb + 7 * 4096,
                                        (const float*)d_in[15], 1, h_i, NI);
  k_gather_mean<<<gGU, 256, 0, stream>>>((const uint4*)x1_i, off_u, csr_i2u, (uint4*)msg, NU);
  k_mfma_gemm64<<<tU, 256, 0, stream>>>(msg, 0, x1_u, wb + 8 * 4096, wb + 9 * 4096,
                                        (const float*)d_in[18], 1, h_u, NU);

  // ---- post linears -> fp32 d_out = [out_u | out_i] ----
  float* out = (float*)d_out;
  k_mfma_postlin<<<tU, 256, 0, stream>>>(h_u, wb + 10 * 4096, (const float*)d_in[21], out, NU);
  k_mfma_postlin<<<tI, 256, 0, stream>>>(h_i, wb + 11 * 4096, (const float*)d_in[23],
                                         out + (size_t)NU * 32, NI);
}

// Round 6
// 607.882 us; speedup vs baseline: 8.6679x; 1.1363x over previous
//
#include <hip/hip_runtime.h>

// RGCN: hetero 2-layer GraphConv (mean aggr), MI355X.
// R6: (a) gather redesign -- R5's slot-split gather was VALU-bound (74%
// VALUBusy): 17 wave-instr/edge + ~90-instr butterfly tail per wave.
// New: wave = 2 dsts, lane = (half, u32-chunk); 3 instr/edge, no butterfly.
// (b) dispatch fusion: pre-linears, per-layer gathers, per-layer conv GEMMs,
// post-linears, degree counts each merged into one dual dispatch.
// CSR build (bucketed two-pass) unchanged from R5.

#define FDIM 64
typedef unsigned short u16;
typedef unsigned int u32;
typedef __bf16 bf16x8 __attribute__((ext_vector_type(8)));
typedef float f32x4 __attribute__((ext_vector_type(4)));

__device__ __forceinline__ u16 f2bf(float x) {  // RNE
  u32 b = __builtin_bit_cast(u32, x);
  b += 0x7FFFu + ((b >> 16) & 1u);
  return (u16)(b >> 16);
}
__device__ __forceinline__ float blo(u32 p) { return __builtin_bit_cast(float, p << 16); }
__device__ __forceinline__ float bhi(u32 p) { return __builtin_bit_cast(float, p & 0xffff0000u); }

// ---- weight conversion: 12 arrays fp32 -> bf16, optional +I (skip fold) ----
struct WTab {
  const float* src[12];
  u16* dst[12];
  int rows[12];
  int addI[12];
};
__global__ __launch_bounds__(256) void k_wconv(WTab p) {
  int b = blockIdx.x;
  const float* s = p.src[b];
  u16* d = p.dst[b];
  int n = p.rows[b] * 64;
  int addI = p.addI[b];
  for (int i = threadIdx.x; i < n; i += 256) {
    float v = s[i];
    if (addI && (i >> 6) == (i & 63)) v += 1.0f;
    d[i] = f2bf(v);
  }
}

// ---- fused degree count for both edge types ----
__global__ __launch_bounds__(256) void k_count2(const int* __restrict__ dstA, int E,
                                                int* __restrict__ cntA,
                                                const int* __restrict__ dstB,
                                                int* __restrict__ cntB) {
  int i = blockIdx.x * 256 + threadIdx.x;
  if (i < E) atomicAdd(&cntA[dstA[i]], 1);
  else if (i < 2 * E) atomicAdd(&cntB[dstB[i - E]], 1);
}

__global__ __launch_bounds__(256) void k_scan1(const int* __restrict__ cnt, int n,
                                               int* __restrict__ excl,
                                               int* __restrict__ partials) {
  __shared__ int sd[256];
  int t = threadIdx.x;
  int base = blockIdx.x * 2048 + t * 8;
  int v[8]; int local = 0;
#pragma unroll
  for (int i = 0; i < 8; ++i) {
    int idx = base + i;
    int x = (idx < n) ? cnt[idx] : 0;
    v[i] = x; local += x;
  }
  sd[t] = local; __syncthreads();
  int sum = local;
  for (int off = 1; off < 256; off <<= 1) {
    int x = (t >= off) ? sd[t - off] : 0;
    __syncthreads();
    sum += x; sd[t] = sum;
    __syncthreads();
  }
  if (t == 255) partials[blockIdx.x] = sum;
  int run = sum - local;
#pragma unroll
  for (int i = 0; i < 8; ++i) {
    int idx = base + i;
    if (idx < n) excl[idx] = run;
    run += v[i];
  }
}

__global__ __launch_bounds__(256) void k_scan2(int* __restrict__ partials, int nb) {
  __shared__ int sd[256];
  int t = threadIdx.x;
  int v = (t < nb) ? partials[t] : 0;
  sd[t] = v; __syncthreads();
  int sum = v;
  for (int off = 1; off < 256; off <<= 1) {
    int x = (t >= off) ? sd[t - off] : 0;
    __syncthreads();
    sum += x; sd[t] = sum;
    __syncthreads();
  }
  if (t < nb) partials[t] = sum - v;
}

__global__ __launch_bounds__(256) void k_scan3(int* __restrict__ off,
                                               const int* __restrict__ partials, int n,
                                               int total, int* __restrict__ cursor,
                                               int shift, int* __restrict__ gcurb) {
  int idx = blockIdx.x * 256 + threadIdx.x;
  if (idx < n) {
    int v = off[idx] + partials[idx >> 11];
    off[idx] = v;
    cursor[idx] = v;
    if ((idx & ((1 << shift) - 1)) == 0) gcurb[idx >> shift] = v;
  }
  if (idx == 0) off[n] = total;
}

// ---- Pass A: bin edges into bucket-grouped (src,dst) pairs ----
#define PA_C 4096
__global__ __launch_bounds__(256) void k_binA(const int* __restrict__ src,
                                              const int* __restrict__ dst, int E,
                                              int shift, int nb,
                                              int* __restrict__ gcurb,
                                              int2* __restrict__ aux) {
  __shared__ int cnt[512];
  __shared__ int base[512];
  int t = threadIdx.x;
  int e0 = blockIdx.x * PA_C;
  int n = min(PA_C, E - e0);
  for (int b = t; b < nb; b += 256) cnt[b] = 0;
  __syncthreads();
  int ls[16], ld[16];
#pragma unroll
  for (int i = 0; i < 16; ++i) {
    int r = t + i * 256;
    if (r < n) {
      ls[i] = src[e0 + r];
      ld[i] = dst[e0 + r];
      atomicAdd(&cnt[ld[i] >> shift], 1);
    }
  }
  __syncthreads();
  for (int b = t; b < nb; b += 256) {
    int c = cnt[b];
    base[b] = c ? atomicAdd(&gcurb[b], c) : 0;
  }
  __syncthreads();
  for (int b = t; b < nb; b += 256) cnt[b] = 0;
  __syncthreads();
#pragma unroll
  for (int i = 0; i < 16; ++i) {
    int r = t + i * 256;
    if (r < n) {
      int b = ld[i] >> shift;
      int p = base[b] + atomicAdd(&cnt[b], 1);
      aux[p] = make_int2(ls[i], ld[i]);
    }
  }
}

// ---- Pass B: one block per bucket; LDS cursors + LDS-staged csr region ----
__global__ __launch_bounds__(256) void k_binB(const int2* __restrict__ aux,
                                              const int* __restrict__ off,
                                              int shift, int N,
                                              int* __restrict__ cur,
                                              int* __restrict__ csr) {
  __shared__ int stage[4096];
  __shared__ int lcur[512];
  int b = blockIdx.x;
  int d0 = b << shift;
  int d1 = min(d0 + (1 << shift), N);
  int r0 = off[d0], r1 = off[d1];
  int RS = r1 - r0;
  int t = threadIdx.x;
  if (RS <= 4096) {
    for (int i = t; i < d1 - d0; i += 256) lcur[i] = off[d0 + i] - r0;
    __syncthreads();
    for (int i = t; i < RS; i += 256) {
      int2 p = aux[r0 + i];
      int pos = atomicAdd(&lcur[p.y - d0], 1);
      stage[pos] = p.x;
    }
    __syncthreads();
    for (int i = t; i < RS; i += 256) csr[r0 + i] = stage[i];
  } else {
    for (int i = t; i < RS; i += 256) {
      int2 p = aux[r0 + i];
      int pos = atomicAdd(&cur[p.y], 1);
      csr[pos] = p.x;
    }
  }
}

// ---- dual gather-mean: wave = 2 dsts; lane = (half h, u32 chunk c) ----
// Per iteration per wave: 1 csr dword (2 addrs) + 1 xs u32 (2 rows x 128B)
// + 4 VALU -> ~3 instr/edge, no cross-lane reduction.
struct GathSide {
  const u32* xs; const int* off; const int* csr; u32* msg; int N; int nblk;
};
__global__ __launch_bounds__(256) void k_dual_gather(GathSide A, GathSide B) {
  int bid = blockIdx.x;
  const GathSide& P = (bid < A.nblk) ? A : B;
  if (bid >= A.nblk) bid -= A.nblk;
  int lane = threadIdx.x & 63;
  int h = lane >> 5, c = lane & 31;
  int d = bid * 8 + (int)(threadIdx.x >> 6) * 2 + h;
  if (d >= P.N) return;
  int beg = P.off[d];
  int deg = P.off[d + 1] - beg;
  const u32* xs = P.xs;
  const int* csr = P.csr;
  float l0 = 0.f, h0 = 0.f, l1 = 0.f, h1 = 0.f;
  int j = 0;
  for (; j + 2 <= deg; j += 2) {
    int s0 = csr[beg + j];
    int s1 = csr[beg + j + 1];
    u32 p0 = xs[(size_t)s0 * 32 + c];
    u32 p1 = xs[(size_t)s1 * 32 + c];
    l0 += blo(p0); h0 += bhi(p0);
    l1 += blo(p1); h1 += bhi(p1);
  }
  if (j < deg) {
    u32 p = xs[(size_t)csr[beg + j] * 32 + c];
    l0 += blo(p); h0 += bhi(p);
  }
  float sc = 1.0f / fmaxf((float)deg, 1.0f);
  P.msg[(size_t)d * 32 + c] = (u32)f2bf((l0 + l1) * sc) | ((u32)f2bf((h0 + h1) * sc) << 16);
}

// ---- dual MFMA GEMM: Y[N,64](bf16) = act( A1 @ W1^T [+ A2 @ W2^T] + bias )
// 128-row tile, wave = 32 rows x 64 cols, direct fragment loads, no LDS.
// Layouts (m89/m91/m120): A-frag A[m=lane&15][k=q*8+j]; B-frag = rows of W;
// C/D col=lane&15, row=q*4+reg.
struct GemmSide {
  const void* A1; const u16* A2; const u16* W1; const u16* W2;
  const float* bias; u16* Y; int N; int a1fp32; int dorelu; int nblk;
};
__device__ __forceinline__ void gemm64_body(const GemmSide& P, int bid) {
  const int t = threadIdx.x;
  const int w = t >> 6, lane = t & 63;
  const int c = lane & 15, q = lane >> 4;
  const int row0 = bid * 128 + w * 32;

  bf16x8 zf;
#pragma unroll
  for (int i = 0; i < 8; ++i) zf[i] = (__bf16)0.0f;

  f32x4 acc[2][4];
#pragma unroll
  for (int ms = 0; ms < 2; ++ms)
#pragma unroll
    for (int n = 0; n < 4; ++n) acc[ms][n] = f32x4{0.f, 0.f, 0.f, 0.f};

  const int nh = (P.A2 != nullptr) ? 2 : 1;
  for (int hh = 0; hh < nh; ++hh) {
    const u16* W = hh ? P.W2 : P.W1;
    bf16x8 bfr[4][2];
#pragma unroll
    for (int n = 0; n < 4; ++n)
#pragma unroll
      for (int kc = 0; kc < 2; ++kc)
        bfr[n][kc] = *(const bf16x8*)(W + (n * 16 + c) * 64 + kc * 32 + q * 8);
    bf16x8 afr[2][2];
#pragma unroll
    for (int ms = 0; ms < 2; ++ms) {
      int row = row0 + ms * 16 + c;
      bool ok = row < P.N;
#pragma unroll
      for (int kc = 0; kc < 2; ++kc) {
        if (hh == 0 && P.a1fp32) {
          bf16x8 v = zf;
          if (ok) {
            const float* Af = (const float*)P.A1 + (size_t)row * 64 + kc * 32 + q * 8;
            float4 u0 = *(const float4*)Af;
            float4 u1 = *(const float4*)(Af + 4);
            v[0] = (__bf16)u0.x; v[1] = (__bf16)u0.y; v[2] = (__bf16)u0.z; v[3] = (__bf16)u0.w;
            v[4] = (__bf16)u1.x; v[5] = (__bf16)u1.y; v[6] = (__bf16)u1.z; v[7] = (__bf16)u1.w;
          }
          afr[ms][kc] = v;
        } else {
          const u16* Ab = (hh == 0) ? (const u16*)P.A1 : P.A2;
          afr[ms][kc] = ok ? *(const bf16x8*)(Ab + (size_t)row * 64 + kc * 32 + q * 8) : zf;
        }
      }
    }
#pragma unroll
    for (int n = 0; n < 4; ++n)
#pragma unroll
      for (int ms = 0; ms < 2; ++ms)
#pragma unroll
        for (int kc = 0; kc < 2; ++kc)
          acc[ms][n] = __builtin_amdgcn_mfma_f32_16x16x32_bf16(afr[ms][kc], bfr[n][kc],
                                                               acc[ms][n], 0, 0, 0);
  }
#pragma unroll
  for (int n = 0; n < 4; ++n) {
    float bv = P.bias[n * 16 + c];
#pragma unroll
    for (int ms = 0; ms < 2; ++ms) {
#pragma unroll
      for (int r = 0; r < 4; ++r) {
        int row = row0 + ms * 16 + q * 4 + r;
        if (row < P.N) {
          float v = acc[ms][n][r] + bv;
          if (P.dorelu) v = fmaxf(v, 0.f);
          P.Y[(size_t)row * 64 + n * 16 + c] = f2bf(v);
        }
      }
    }
  }
}
__global__ __launch_bounds__(256) void k_dual_gemm(GemmSide A, GemmSide B) {
  if ((int)blockIdx.x < A.nblk) gemm64_body(A, blockIdx.x);
  else gemm64_body(B, blockIdx.x - A.nblk);
}

// ---- dual MFMA post linear: Y[N,32](fp32) = A(bf16) @ W[32,64]^T + bias ----
struct PostSide {
  const u16* A; const u16* W; const float* bias; float* Y; int N; int nblk;
};
__device__ __forceinline__ void postlin_body(const PostSide& P, int bid) {
  const int t = threadIdx.x;
  const int w = t >> 6, lane = t & 63;
  const int c = lane & 15, q = lane >> 4;
  const int row0 = bid * 128 + w * 32;

  bf16x8 zf;
#pragma unroll
  for (int i = 0; i < 8; ++i) zf[i] = (__bf16)0.0f;

  f32x4 acc[2][2];
#pragma unroll
  for (int ms = 0; ms < 2; ++ms)
#pragma unroll
    for (int n = 0; n < 2; ++n) acc[ms][n] = f32x4{0.f, 0.f, 0.f, 0.f};

  bf16x8 bfr[2][2];
#pragma unroll
  for (int n = 0; n < 2; ++n)
#pragma unroll
    for (int kc = 0; kc < 2; ++kc)
      bfr[n][kc] = *(const bf16x8*)(P.W + (n * 16 + c) * 64 + kc * 32 + q * 8);
  bf16x8 afr[2][2];
#pragma unroll
  for (int ms = 0; ms < 2; ++ms) {
    int row = row0 + ms * 16 + c;
    bool ok = row < P.N;
#pragma unroll
    for (int kc = 0; kc < 2; ++kc)
      afr[ms][kc] = ok ? *(const bf16x8*)(P.A + (size_t)row * 64 + kc * 32 + q * 8) : zf;
  }
#pragma unroll
  for (int n = 0; n < 2; ++n)
#pragma unroll
    for (int ms = 0; ms < 2; ++ms)
#pragma unroll
      for (int kc = 0; kc < 2; ++kc)
        acc[ms][n] = __builtin_amdgcn_mfma_f32_16x16x32_bf16(afr[ms][kc], bfr[n][kc],
                                                             acc[ms][n], 0, 0, 0);
#pragma unroll
  for (int n = 0; n < 2; ++n) {
    float bv = P.bias[n * 16 + c];
#pragma unroll
    for (int ms = 0; ms < 2; ++ms) {
#pragma unroll
      for (int r = 0; r < 4; ++r) {
        int row = row0 + ms * 16 + q * 4 + r;
        if (row < P.N) P.Y[(size_t)row * 32 + n * 16 + c] = acc[ms][n][r] + bv;
      }
    }
  }
}
__global__ __launch_bounds__(256) void k_dual_postlin(PostSide A, PostSide B) {
  if ((int)blockIdx.x < A.nblk) postlin_body(A, blockIdx.x);
  else postlin_body(B, blockIdx.x - A.nblk);
}

extern "C" void kernel_launch(void* const* d_in, const int* in_sizes, int n_in,
                              void* d_out, int out_size, void* d_ws, size_t ws_size,
                              hipStream_t stream) {
  const float* x_user = (const float*)d_in[0];
  const float* x_item = (const float*)d_in[1];
  const int* ei_u2i = (const int*)d_in[2];
  const int* ei_i2u = (const int*)d_in[3];

  const int NU = in_sizes[0] / FDIM;
  const int NI = in_sizes[1] / FDIM;
  const int E = in_sizes[2] / 2;

  // ---- workspace ----
  u16* wsu = (u16*)d_ws;
  u16* h_u = wsu;   wsu += (size_t)NU * FDIM;
  u16* h_i = wsu;   wsu += (size_t)NI * FDIM;
  u16* x1_u = wsu;  wsu += (size_t)NU * FDIM;
  u16* x1_i = wsu;  wsu += (size_t)NI * FDIM;
  u16* msg_i = wsu; wsu += (size_t)NI * FDIM;
  u16* msg_u = wsu; wsu += (size_t)NU * FDIM;
  u16* wb = wsu;    wsu += 12 * 4096;
  int2* aux = (int2*)wsu;
  int* wsi = (int*)(aux + E);
  int* off_i = wsi;    wsi += NI + 1;
  int* off_u = wsi;    wsi += NU + 1;
  int* cur_i = wsi;    wsi += NI;   // contiguous with cur_u: single memset
  int* cur_u = wsi;    wsi += NU;
  int* partials = wsi; wsi += 256;
  int* gcurb_i = wsi;  wsi += 512;
  int* gcurb_u = wsi;  wsi += 512;
  int* csr_u2i = wsi;  wsi += E;
  int* csr_i2u = wsi;  wsi += E;

  const int* u2i_src = ei_u2i;
  const int* u2i_dst = ei_u2i + E;
  const int* i2u_src = ei_i2u;
  const int* i2u_dst = ei_i2u + E;

  const int gA = (E + PA_C - 1) / PA_C;
  const int tU = (NU + 127) / 128;
  const int tI = (NI + 127) / 128;
  const int bI = (NI + 2047) / 2048;
  const int bU = (NU + 2047) / 2048;
  const int gGI = (NI + 7) / 8;
  const int gGU = (NU + 7) / 8;
  const int SH_I = 8, SH_U = 9;
  const int nbI = (NI + (1 << SH_I) - 1) >> SH_I;
  const int nbU = (NU + (1 << SH_U) - 1) >> SH_U;

  // ---- weight conversion (skip folded: wroot + I) ----
  WTab tab;
  const int widx[12] = {4, 6, 8, 10, 11, 13, 14, 16, 17, 19, 20, 22};
  const int addI[12] = {0, 0, 0, 1, 0, 1, 0, 1, 0, 1, 0, 0};
  const int rows_[12] = {64, 64, 64, 64, 64, 64, 64, 64, 64, 64, 32, 32};
  for (int i = 0; i < 12; ++i) {
    tab.src[i] = (const float*)d_in[widx[i]];
    tab.dst[i] = wb + i * 4096;
    tab.rows[i] = rows_[i];
    tab.addI[i] = addI[i];
  }
  k_wconv<<<12, 256, 0, stream>>>(tab);

  // ---- pre linears (dual): fp32 x -> bf16 h ----
  {
    GemmSide a{x_user, nullptr, wb + 0 * 4096, nullptr, (const float*)d_in[5],
               h_u, NU, 1, 0, tU};
    GemmSide b{x_item, nullptr, wb + 1 * 4096, nullptr, (const float*)d_in[7],
               h_i, NI, 1, 0, tI};
    k_dual_gemm<<<tU + tI, 256, 0, stream>>>(a, b);
  }

  // ---- CSR build ----
  hipMemsetAsync(cur_i, 0, (size_t)(NI + NU) * sizeof(int), stream);
  k_count2<<<(2 * E + 255) / 256, 256, 0, stream>>>(u2i_dst, E, cur_i, i2u_dst, cur_u);
  k_scan1<<<bI, 256, 0, stream>>>(cur_i, NI, off_i, partials);
  k_scan2<<<1, 256, 0, stream>>>(partials, bI);
  k_scan3<<<(NI + 255) / 256, 256, 0, stream>>>(off_i, partials, NI, E, cur_i, SH_I, gcurb_i);
  k_binA<<<gA, 256, 0, stream>>>(u2i_src, u2i_dst, E, SH_I, nbI, gcurb_i, aux);
  k_binB<<<nbI, 256, 0, stream>>>(aux, off_i, SH_I, NI, cur_i, csr_u2i);
  k_scan1<<<bU, 256, 0, stream>>>(cur_u, NU, off_u, partials);
  k_scan2<<<1, 256, 0, stream>>>(partials, bU);
  k_scan3<<<(NU + 255) / 256, 256, 0, stream>>>(off_u, partials, NU, E, cur_u, SH_U, gcurb_u);
  k_binA<<<gA, 256, 0, stream>>>(i2u_src, i2u_dst, E, SH_U, nbU, gcurb_u, aux);
  k_binB<<<nbU, 256, 0, stream>>>(aux, off_u, SH_U, NU, cur_u, csr_i2u);

  // ---- layer 1: both gathers in one dispatch, both convs in one ----
  {
    GathSide a{(const u32*)h_u, off_i, csr_u2i, (u32*)msg_i, NI, gGI};
    GathSide b{(const u32*)h_i, off_u, csr_i2u, (u32*)msg_u, NU, gGU};
    k_dual_gather<<<gGI + gGU, 256, 0, stream>>>(a, b);
  }
  {
    GemmSide a{msg_i, h_i, wb + 2 * 4096, wb + 3 * 4096, (const float*)d_in[9],
               x1_i, NI, 0, 1, tI};
    GemmSide b{msg_u, h_u, wb + 4 * 4096, wb + 5 * 4096, (const float*)d_in[12],
               x1_u, NU, 0, 1, tU};
    k_dual_gemm<<<tI + tU, 256, 0, stream>>>(a, b);
  }

  // ---- layer 2 (outputs overwrite h_i / h_u) ----
  {
    GathSide a{(const u32*)x1_u, off_i, csr_u2i, (u32*)msg_i, NI, gGI};
    GathSide b{(const u32*)x1_i, off_u, csr_i2u, (u32*)msg_u, NU, gGU};
    k_dual_gather<<<gGI + gGU, 256, 0, stream>>>(a, b);
  }
  {
    GemmSide a{msg_i, x1_i, wb + 6 * 4096, wb + 7 * 4096, (const float*)d_in[15],
               h_i, NI, 0, 1, tI};
    GemmSide b{msg_u, x1_u, wb + 8 * 4096, wb + 9 * 4096, (const float*)d_in[18],
               h_u, NU, 0, 1, tU};
    k_dual_gemm<<<tI + tU, 256, 0, stream>>>(a, b);
  }

  // ---- post linears (dual) -> fp32 d_out = [out_u | out_i] ----
  {
    float* out = (float*)d_out;
    PostSide a{h_u, wb + 10 * 4096, (const float*)d_in[21], out, NU, tU};
    PostSide b{h_i, wb + 11 * 4096, (const float*)d_in[23], out + (size_t)NU * 32, NI, tI};
    k_dual_postlin<<<tU + tI, 256, 0, stream>>>(a, b);
  }
}